// Round 4
// baseline (698.518 us; speedup 1.0000x reference)
//
#include <hip/hip_runtime.h>
#include <hip/hip_bf16.h>
#include <math.h>

// HMF block, round 8: k_cost spill fix verified (968->661; k_cost out of
// top-5). New top: k_conv3 @128 µs, latency-bound (MfmaUtil 11%, VALU 8%,
// HBM 14%, Occ 18.9% grid-limited, 5.9M LDS bank conflicts).
// k_conv3 restructured:
//  - 256 threads / 4 waves (2x2 px/co split, acc[4][4]) -> 2x waves/CU
//  - WS double-buffered + register prefetch: weight loads for step+1
//    issued before MFMAs, ds_write after -> 1 barrier/pos (was 2),
//    L2 latency hidden under compute
//  - XOR swizzle (off ^= rc&8 u16 units) on IN/WS write+read to break
//    the row r/r+8 bank alias (80B stride: 8*20 banks = 160 = 0 mod 32)
// Everything else identical to verified round 7.

typedef __hip_bfloat16 bf16;
typedef unsigned short u16;
typedef __attribute__((ext_vector_type(8))) __bf16 bf16x8;
typedef __attribute__((ext_vector_type(4))) float f4;

#define DEVI static __device__ __forceinline__
DEVI float bf2f(bf16 x) { return __bfloat162float(x); }
DEVI bf16  f2bf(float x) { return __float2bfloat16(x); }
DEVI u16 bfbits(float x) { bf16 h = f2bf(x); return *(u16*)&h; }
DEVI float sigmoidf_(float x) { return 1.0f / (1.0f + expf(-x)); }

constexpr int B_ = 4, C_ = 128, H_ = 96, W_ = 320, CM = 32, D_ = 32;
constexpr int HW = H_ * W_;              // 30720
constexpr int QPLANE = CM * HW;          // 983040
constexpr int XN = B_ * C_ * HW;         // 15728640
constexpr int PLN = B_ * D_ * HW;        // 3932160

// scratch slots (floats): q=0 | k=1 | Cv=2 | da=3 | Pf=4 ; xf overlays 4-7.
__device__ __align__(16) float g_scratch[8 * PLN];
__device__ __align__(16) u16   g_fused[XN];          // bf16 NHWC
__device__ __align__(16) u16   g_wt[9 * 128 * 128];  // bf16 [pos][co][ci]
__device__ float g_ysum[512];
__device__ float g_se[512];
__device__ int   g_flag[1];

DEVI float ldin(const void* p, int i, int isb) {
    float v;
    if (isb) v = bf2f(((const bf16*)p)[i]);
    else     v = ((const float*)p)[i];
    return v;
}
DEVI void stout(void* p, int i, float v, int isb) {
    if (isb) ((bf16*)p)[i] = f2bf(v);
    else     ((float*)p)[i] = v;
}

// ---------------------------------------------------------------------------
// K0: dtype detect (t_feat + wq) + ysum zero.
__global__ __launch_bounds__(256) void k_detect(
    const void* __restrict__ t, const void* __restrict__ wqp)
{
    __shared__ int bad;
    int tid = threadIdx.x;
    if (tid == 0) bad = 0;
    __syncthreads();
    int mybad = 0;
    for (int i = tid; i < 4096; i += 256) {
        float v = bf2f(((const bf16*)t)[i]);
        if (!(v == v) || fabsf(v) > 64.0f) mybad = 1;
        float u = bf2f(((const bf16*)wqp)[i]);
        if (!(u == u) || fabsf(u) > 64.0f) mybad = 1;
    }
    if (mybad) atomicOr(&bad, 1);
    g_ysum[tid] = 0.f;
    g_ysum[tid + 256] = 0.f;
    __syncthreads();
    if (tid == 0) g_flag[0] = bad ? 0 : 1;
}

// K0b: weight transform w_rd[co][ci][pos] -> g_wt[pos][co][ci] (bf16)
__global__ __launch_bounds__(256) void k_wprep(
    const void* __restrict__ w_rd, u16* __restrict__ gw)
{
    int isb = g_flag[0];
    int i = blockIdx.x * 256 + threadIdx.x;
    if (i >= 9 * 128 * 128) return;
    int pos = i >> 14, rem = i & 16383, co = rem >> 7, ci = rem & 127;
    gw[i] = bfbits(ldin(w_rd, (co * 128 + ci) * 9 + pos, isb));
}

// ---------------------------------------------------------------------------
// K1: q = l2norm(conv1x1(t,wq,bq)), k = l2norm(conv1x1(s,wkc,bkc))
__global__ __launch_bounds__(320) void k_qk(
    const void* __restrict__ t_feat, const void* __restrict__ s_feat,
    const void* __restrict__ wq, const void* __restrict__ bq,
    const void* __restrict__ wkc, const void* __restrict__ bkc,
    float* __restrict__ qout, float* __restrict__ kout)
{
    __shared__ float WST[C_ * CM];   // [c][o]
    __shared__ float BS[CM];
    int isb = g_flag[0];
    int h = blockIdx.x, b = blockIdx.y, which = blockIdx.z;
    const void* in = which ? s_feat : t_feat;
    const void* wm = which ? wkc : wq;
    const void* bb = which ? bkc : bq;
    float* out = which ? kout : qout;
    int tid = threadIdx.x;
    for (int i = tid; i < C_ * CM; i += 320) {
        int o = i >> 7, c = i & 127;
        WST[c * CM + o] = ldin(wm, i, isb);
    }
    if (tid < CM) BS[tid] = ldin(bb, tid, isb);
    __syncthreads();
    int w = tid;
    float acc[CM];
    #pragma unroll
    for (int o = 0; o < CM; o++) acc[o] = BS[o];
    int base = (b * C_) * HW + h * W_ + w;
    for (int c = 0; c < C_; c++) {
        float v = ldin(in, base + c * HW, isb);
        #pragma unroll
        for (int o = 0; o < CM; o++) acc[o] += v * WST[c * CM + o];
    }
    float n = 0.f;
    #pragma unroll
    for (int o = 0; o < CM; o++) n += acc[o] * acc[o];
    float s = 1.0f / fmaxf(sqrtf(n), 1e-12f);
    float* op = out + (b * CM) * HW + h * W_ + w;
    #pragma unroll
    for (int o = 0; o < CM; o++) op[o * HW] = acc[o] * s;
}

// ---------------------------------------------------------------------------
// K2: warp + sim + tanh -> Cv; da = sigmoid(w_da @ [q; mean_d(warped)])
// Spill-free restructure: no q[32] array; peak live = qp+dqa+km = 96 floats.
__global__ __launch_bounds__(320, 3) void k_cost(
    const float* __restrict__ qbuf, const float* __restrict__ kbuf,
    const void* __restrict__ metric, const void* __restrict__ disps,
    const void* __restrict__ directs, const void* __restrict__ alpha_p,
    const void* __restrict__ beta_p, const void* __restrict__ w_da,
    const void* __restrict__ b_da,
    float* __restrict__ Cv, float* __restrict__ da)
{
    __shared__ float KS[CM][W_];
    __shared__ float MS[CM][CM];
    __shared__ float WDA[D_ * 64];
    __shared__ float BDA[D_];
    __shared__ float SH[D_];
    int isb = g_flag[0];
    int h = blockIdx.x, b = blockIdx.y, tid = threadIdx.x, w = tid;
    for (int i = tid; i < CM * CM; i += 320) {
        int c = i >> 5, d = i & 31;
        MS[c][d] = 0.5f * (ldin(metric, c * CM + d, isb) + ldin(metric, d * CM + c, isb));
    }
    for (int i = tid; i < D_ * 64; i += 320) WDA[i] = ldin(w_da, i, isb);
    if (tid < D_) {
        BDA[tid] = ldin(b_da, tid, isb);
        SH[tid] = ldin(disps, tid, isb) * ldin(directs, b, isb) * (float)(W_ - 1);
    }
    const float* kp = kbuf + b * QPLANE + h * W_;
    for (int c = 0; c < CM; c++) KS[c][w] = kp[c * HW + w];
    __syncthreads();

    // Phase A: stream q per channel -> qp (metric proj) + dqa (da q-part).
    float qp[CM], dqa[CM];
    #pragma unroll
    for (int d = 0; d < CM; d++) { qp[d] = 0.f; dqa[d] = 0.f; }
    const float* qpp = qbuf + b * QPLANE + h * W_ + w;
    for (int c = 0; c < CM; c++) {
        float v = qpp[c * HW];
        #pragma unroll
        for (int d = 0; d < CM; d++) qp[d] += v * MS[c][d];
        #pragma unroll
        for (int d = 0; d < D_; d++) dqa[d] += v * WDA[d * 64 + c];
    }

    // Phase B: warp + sim + tanh; km accumulates over d. qp dies after this.
    float km[CM];
    #pragma unroll
    for (int c = 0; c < CM; c++) km[c] = 0.f;
    float alpha = ldin(alpha_p, 0, isb), beta = ldin(beta_p, 0, isb);
    float* cvp = Cv + (b * D_) * HW + h * W_ + w;
    for (int d = 0; d < D_; d++) {
        float px = fminf(fmaxf((float)w + SH[d], 0.f), (float)(W_ - 1));
        int x0 = (int)floorf(px);
        int x1 = min(x0 + 1, W_ - 1);
        float f = px - (float)x0;
        float sim = 0.f;
        #pragma unroll
        for (int c = 0; c < CM; c++) {
            float g0 = KS[c][x0], g1 = KS[c][x1];
            float val = g0 * (1.0f - f) + g1 * f;
            sim += qp[c] * val;
            km[c] += val;
        }
        cvp[d * HW] = tanhf(alpha * sim + beta);
    }

    // Phase C: da from dqa + km (qp dead; live = 64 floats).
    #pragma unroll
    for (int c = 0; c < CM; c++) km[c] *= (1.0f / (float)D_);
    float* dap = da + (b * D_) * HW + h * W_ + w;
    for (int d = 0; d < D_; d++) {
        float s = BDA[d] + dqa[d];
        #pragma unroll
        for (int c = 0; c < CM; c++) s += WDA[d * 64 + 32 + c] * km[c];
        dap[d * HW] = sigmoidf_(s);
    }
}

// ---------------------------------------------------------------------------
// K3: Cf = 3x3 conv(Cv) * da -> softmax over d -> Pf (f32) + P out
__global__ __launch_bounds__(320) void k_cf_softmax(
    const float* __restrict__ Cv, const float* __restrict__ da,
    const void* __restrict__ w_cf, const void* __restrict__ b_cf,
    float* __restrict__ Pf, void* __restrict__ dout)
{
    __shared__ float R[3][322];
    int isb = g_flag[0];
    int h = blockIdx.x, b = blockIdx.y, tid = threadIdx.x, w = tid;
    float wcf[9];
    #pragma unroll
    for (int i = 0; i < 9; i++) wcf[i] = ldin(w_cf, i, isb);
    float bcf = ldin(b_cf, 0, isb);
    float vals[D_];
    for (int d = 0; d < D_; d++) {
        const float* base = Cv + ((b * D_ + d) * H_) * W_;
        #pragma unroll
        for (int r = 0; r < 3; r++) {
            int hh = h + r - 1;
            R[r][w + 1] = (hh >= 0 && hh < H_) ? base[hh * W_ + w] : 0.f;
        }
        if (tid == 0) {
            R[0][0] = R[1][0] = R[2][0] = 0.f;
            R[0][321] = R[1][321] = R[2][321] = 0.f;
        }
        __syncthreads();
        float s = bcf;
        #pragma unroll
        for (int r = 0; r < 3; r++)
            #pragma unroll
            for (int kw = 0; kw < 3; kw++)
                s += R[r][w + kw] * wcf[r * 3 + kw];
        vals[d] = s * da[((b * D_ + d) * H_ + h) * W_ + w];
        __syncthreads();
    }
    float m = vals[0];
    #pragma unroll
    for (int d = 1; d < D_; d++) m = fmaxf(m, vals[d]);
    float sum = 0.f;
    #pragma unroll
    for (int d = 0; d < D_; d++) { vals[d] = expf(vals[d] - m); sum += vals[d]; }
    float inv = 1.0f / sum;
    int o = (b * D_) * HW + h * W_ + w;
    #pragma unroll
    for (int d = 0; d < D_; d++) {
        float p = vals[d] * inv;
        Pf[o + d * HW] = p;
        stout(dout, XN + o + d * HW, p, isb);
    }
}

// ---------------------------------------------------------------------------
// K4: cost = w_ex@P+b_ex; g = sigmoid(w_fg@[t;cost]);
//     fused = g*t+(1-g)*cost  -> g_fused (bf16, NHWC)
__global__ __launch_bounds__(320) void k_fuse(
    const float* __restrict__ Pf, const void* __restrict__ t_feat,
    const void* __restrict__ w_ex, const void* __restrict__ b_ex,
    const void* __restrict__ w_fg, const void* __restrict__ b_fg,
    u16* __restrict__ gf)
{
    __shared__ float WEX[C_ * D_];   // [c][d]
    __shared__ float BEX[C_];
    __shared__ float WFG[2 * C_];
    int isb = g_flag[0];
    int h = blockIdx.x, b = blockIdx.y, tid = threadIdx.x, w = tid;
    for (int i = tid; i < C_ * D_; i += 320) WEX[i] = ldin(w_ex, i, isb);
    if (tid < C_) BEX[tid] = ldin(b_ex, tid, isb);
    for (int i = tid; i < 2 * C_; i += 320) WFG[i] = ldin(w_fg, i, isb);
    __syncthreads();
    float p[D_];
    const float* pp = Pf + (b * D_) * HW + h * W_ + w;
    #pragma unroll
    for (int d = 0; d < D_; d++) p[d] = pp[d * HW];
    int tbase = (b * C_) * HW + h * W_ + w;
    float gacc = ldin(b_fg, 0, isb);
    for (int c = 0; c < C_; c++) {
        float cost = BEX[c];
        #pragma unroll
        for (int d = 0; d < D_; d++) cost += WEX[c * D_ + d] * p[d];
        float tv = ldin(t_feat, tbase + c * HW, isb);
        gacc += WFG[c] * tv + WFG[C_ + c] * cost;
    }
    float g = sigmoidf_(gacc);
    unsigned int* gfo = (unsigned int*)gf + ((b * H_ + h) * W_ + w) * 64;
    for (int c = 0; c < C_; c += 2) {
        float c0 = BEX[c], c1 = BEX[c + 1];
        #pragma unroll
        for (int d = 0; d < D_; d++) {
            c0 += WEX[c * D_ + d] * p[d];
            c1 += WEX[(c + 1) * D_ + d] * p[d];
        }
        float t0 = ldin(t_feat, tbase + c * HW, isb);
        float t1 = ldin(t_feat, tbase + (c + 1) * HW, isb);
        float v0 = g * t0 + (1.0f - g) * c0;
        float v1 = g * t1 + (1.0f - g) * c1;
        gfo[c >> 1] = ((unsigned int)bfbits(v1) << 16) | bfbits(v0);
    }
}

// ---------------------------------------------------------------------------
// K5: x = conv3x3(fused)+b_rd via MFMA implicit GEMM.
// grid (10, 24, 4): 32w x 4h x 128co tile; block 256 (4 waves, 2x2 split).
// Wave (wr,wc): px range wr*64 (4 m-tiles), co range wc*64 (4 n-tiles).
// WS double-buffered with register prefetch (issue-early/write-late);
// XOR swizzle (^ rc&8, u16 units) breaks the 80B-stride r/r+8 bank alias.
__global__ __launch_bounds__(256, 4) void k_conv3(
    const u16* __restrict__ gf, const u16* __restrict__ gw,
    const void* __restrict__ b_rd, float* __restrict__ xf)
{
    __shared__ u16 IN[204 * 40];       // 6x34 halo x 32ci, swizzled
    __shared__ u16 WS[2][128 * 40];    // [buf][co][ci], swizzled
    int isb = g_flag[0];
    int tid = threadIdx.x;
    int wave = tid >> 6, lane = tid & 63;
    int wr = wave >> 1, wc = wave & 1;
    int l15 = lane & 15, kq = lane >> 4;
    int w0 = blockIdx.x * 32, h0 = blockIdx.y * 4, b = blockIdx.z;

    f4 acc[4][4];
    #pragma unroll
    for (int mt = 0; mt < 4; mt++)
        #pragma unroll
        for (int nt = 0; nt < 4; nt++) acc[mt][nt] = (f4){0.f, 0.f, 0.f, 0.f};

    float bias[4];
    #pragma unroll
    for (int nt = 0; nt < 4; nt++) bias[nt] = ldin(b_rd, wc * 64 + nt * 16 + l15, isb);

    // prologue: stage WS[0] with (pos=0, cb=0)
    #pragma unroll
    for (int i = 0; i < 2; i++) {
        int s = tid + i * 256, co = s >> 2, q = s & 3;
        *(uint4*)(&WS[0][co * 40 + ((q * 8) ^ (co & 8))]) =
            *(const uint4*)(gw + ((co << 7) + q * 8));
    }

    int step = 0;
    for (int cb = 0; cb < 128; cb += 32) {
        __syncthreads();   // prev cb's readers of IN are done
        for (int s = tid; s < 204 * 4; s += 256) {
            int p = s >> 2, q = s & 3;
            int hp = p / 34, wp = p - hp * 34;
            int hg = h0 - 1 + hp, wg = w0 - 1 + wp;
            uint4 v = make_uint4(0u, 0u, 0u, 0u);
            if (hg >= 0 && hg < H_ && wg >= 0 && wg < W_)
                v = *(const uint4*)(gf + ((((b * H_ + hg) * W_ + wg) << 7) + cb + q * 8));
            *(uint4*)(&IN[p * 40 + ((q * 8) ^ (p & 8))]) = v;
        }
        __syncthreads();   // IN + WS[step&1] visible
        for (int pos = 0; pos < 9; pos++, step++) {
            int cur = step & 1;
            // prefetch next step's weights into regs (issue-early)
            uint4 wreg0, wreg1;
            int have = (step < 35);
            int pn = (pos == 8) ? 0 : pos + 1;
            int cbn = (pos == 8) ? cb + 32 : cb;
            if (have) {
                int co0 = tid >> 2, q0 = tid & 3;
                wreg0 = *(const uint4*)(gw + (((pn * 128 + co0) << 7) + cbn + q0 * 8));
                int s1 = tid + 256, co1 = s1 >> 2, q1 = s1 & 3;
                wreg1 = *(const uint4*)(gw + (((pn * 128 + co1) << 7) + cbn + q1 * 8));
            }
            // compute pos from WS[cur] / IN
            int kh = pos / 3, kw = pos - kh * 3;
            bf16x8 bfr[4];
            #pragma unroll
            for (int nt = 0; nt < 4; nt++) {
                int co = wc * 64 + nt * 16 + l15;
                bfr[nt] = *(bf16x8*)(&WS[cur][co * 40 + ((kq * 8) ^ (co & 8))]);
            }
            #pragma unroll
            for (int mt = 0; mt < 4; mt++) {
                int px = wr * 64 + mt * 16 + l15;
                int rc = ((px >> 5) + kh) * 34 + (px & 31) + kw;
                bf16x8 afr = *(bf16x8*)(&IN[rc * 40 + ((kq * 8) ^ (rc & 8))]);
                #pragma unroll
                for (int nt = 0; nt < 4; nt++)
                    acc[mt][nt] = __builtin_amdgcn_mfma_f32_16x16x32_bf16(
                        afr, bfr[nt], acc[mt][nt], 0, 0, 0);
            }
            // write-late: stage prefetched weights into the other buffer
            if (have) {
                int co0 = tid >> 2, q0 = tid & 3;
                *(uint4*)(&WS[cur ^ 1][co0 * 40 + ((q0 * 8) ^ (co0 & 8))]) = wreg0;
                int s1 = tid + 256, co1 = s1 >> 2, q1 = s1 & 3;
                *(uint4*)(&WS[cur ^ 1][co1 * 40 + ((q1 * 8) ^ (co1 & 8))]) = wreg1;
            }
            __syncthreads();
        }
    }
    // epilogue: bias, store x (f32 NCHW), SE partial sums
    #pragma unroll
    for (int nt = 0; nt < 4; nt++) {
        int co = wc * 64 + nt * 16 + l15;
        float ps = 0.f;
        #pragma unroll
        for (int mt = 0; mt < 4; mt++) {
            #pragma unroll
            for (int r = 0; r < 4; r++) {
                int px = wr * 64 + mt * 16 + kq * 4 + r;
                float v = acc[mt][nt][r] + bias[nt];
                ps += v;
                xf[((b * C_ + co) * H_ + h0 + (px >> 5)) * W_ + w0 + (px & 31)] = v;
            }
        }
        ps += __shfl_xor(ps, 16);
        ps += __shfl_xor(ps, 32);
        if (lane < 16) atomicAdd(&g_ysum[b * C_ + co], ps);
    }
}

// ---------------------------------------------------------------------------
// K6: SE scale per (b,c)
__global__ __launch_bounds__(512) void k_se(
    const void* __restrict__ w_se1, const void* __restrict__ w_se2)
{
    __shared__ float YM[B_ * C_];
    __shared__ float Y1[B_ * 8];
    int isb = g_flag[0];
    int tid = threadIdx.x;
    YM[tid] = g_ysum[tid] * (1.0f / (float)HW);
    __syncthreads();
    if (tid < 32) {
        int b = tid >> 3, j = tid & 7;
        float s = 0.f;
        for (int c = 0; c < C_; c++) s += YM[b * C_ + c] * ldin(w_se1, j * C_ + c, isb);
        Y1[tid] = fmaxf(s, 0.f);
    }
    __syncthreads();
    int b = tid >> 7, c = tid & 127;
    float s = 0.f;
    #pragma unroll
    for (int j = 0; j < 8; j++) s += Y1[b * 8 + j] * ldin(w_se2, c * 8 + j, isb);
    g_se[tid] = sigmoidf_(s);
}

// K7: out_x = elu(xf32 * se), in detected output dtype
__global__ __launch_bounds__(256) void k_elu(
    const float* __restrict__ xf, void* __restrict__ dout)
{
    int isb = g_flag[0];
    int idx = blockIdx.x * 256 + threadIdx.x;
    if (idx >= XN) return;
    int plane = idx / HW;
    float v = xf[idx] * g_se[plane];
    stout(dout, idx, v > 0.f ? v : expm1f(v), isb);
}

// ---------------------------------------------------------------------------
extern "C" void kernel_launch(void* const* d_in, const int* in_sizes, int n_in,
                              void* d_out, int out_size, void* d_ws, size_t ws_size,
                              hipStream_t stream)
{
    const void* t_feat  = d_in[0];
    const void* s_feat  = d_in[1];
    const void* directs = d_in[2];
    /* d_in[3] image_shape: unused */
    const void* disps   = d_in[4];
    const void* wq      = d_in[5];
    const void* bq      = d_in[6];
    const void* wkc     = d_in[7];
    const void* bkc     = d_in[8];
    const void* metric  = d_in[9];
    const void* alpha   = d_in[10];
    const void* beta    = d_in[11];
    const void* w_cf    = d_in[12];
    const void* b_cf    = d_in[13];
    const void* w_da    = d_in[14];
    const void* b_da    = d_in[15];
    const void* w_ex    = d_in[16];
    const void* b_ex    = d_in[17];
    const void* w_fg    = d_in[18];
    const void* b_fg    = d_in[19];
    const void* w_rd    = d_in[20];
    const void* b_rd    = d_in[21];
    const void* w_se1   = d_in[22];
    const void* w_se2   = d_in[23];
    (void)in_sizes; (void)n_in; (void)out_size; (void)d_ws; (void)ws_size;

    float* base = nullptr;
    (void)hipGetSymbolAddress((void**)&base, HIP_SYMBOL(g_scratch));
    u16* gf = nullptr;
    (void)hipGetSymbolAddress((void**)&gf, HIP_SYMBOL(g_fused));
    u16* gw = nullptr;
    (void)hipGetSymbolAddress((void**)&gw, HIP_SYMBOL(g_wt));
    float* qb = base;
    float* kb = base + PLN;
    float* Cv = base + 2 * PLN;
    float* da = base + 3 * PLN;
    float* Pf = base + 4 * PLN;
    float* xf = base + 4 * PLN;      // overlays Pf (dead after k_fuse)

    k_detect<<<1, 256, 0, stream>>>(t_feat, wq);
    k_wprep<<<576, 256, 0, stream>>>(w_rd, gw);
    k_qk<<<dim3(H_, B_, 2), 320, 0, stream>>>(t_feat, s_feat, wq, bq, wkc, bkc, qb, kb);
    k_cost<<<dim3(H_, B_), 320, 0, stream>>>(qb, kb, metric, disps, directs,
                                             alpha, beta, w_da, b_da, Cv, da);
    k_cf_softmax<<<dim3(H_, B_), 320, 0, stream>>>(Cv, da, w_cf, b_cf, Pf, d_out);
    k_fuse<<<dim3(H_, B_), 320, 0, stream>>>(Pf, t_feat, w_ex, b_ex, w_fg, b_fg, gf);
    k_conv3<<<dim3(10, 24, 4), 256, 0, stream>>>(gf, gw, b_rd, xf);
    k_se<<<1, 512, 0, stream>>>(w_se1, w_se2);
    k_elu<<<(XN + 255) / 256, 256, 0, stream>>>(xf, d_out);
}

// Round 5
// 674.442 us; speedup vs baseline: 1.0357x; 1.0357x over previous
//
#include <hip/hip_runtime.h>
#include <hip/hip_bf16.h>
#include <math.h>

// HMF block, round 9: round-8 post-mortem — __launch_bounds__(256,4) capped
// the unified VGPR file at 128; acc[4][4]=64 regs + ~85 arch regs spilled
// (FETCH 63->154 MB, WRITE 78->128 MB, the round-6 scratch signature;
// MfmaUtil fell 11->8.4%). Swizzle itself was fine (per-op conflicts down).
// Fix: __launch_bounds__(256,3) -> cap ~170 regs, no spill, still 3
// blocks/CU (12 waves/CU, ~37% occupancy). Only change vs round 8.

typedef __hip_bfloat16 bf16;
typedef unsigned short u16;
typedef __attribute__((ext_vector_type(8))) __bf16 bf16x8;
typedef __attribute__((ext_vector_type(4))) float f4;

#define DEVI static __device__ __forceinline__
DEVI float bf2f(bf16 x) { return __bfloat162float(x); }
DEVI bf16  f2bf(float x) { return __float2bfloat16(x); }
DEVI u16 bfbits(float x) { bf16 h = f2bf(x); return *(u16*)&h; }
DEVI float sigmoidf_(float x) { return 1.0f / (1.0f + expf(-x)); }

constexpr int B_ = 4, C_ = 128, H_ = 96, W_ = 320, CM = 32, D_ = 32;
constexpr int HW = H_ * W_;              // 30720
constexpr int QPLANE = CM * HW;          // 983040
constexpr int XN = B_ * C_ * HW;         // 15728640
constexpr int PLN = B_ * D_ * HW;        // 3932160

// scratch slots (floats): q=0 | k=1 | Cv=2 | da=3 | Pf=4 ; xf overlays 4-7.
__device__ __align__(16) float g_scratch[8 * PLN];
__device__ __align__(16) u16   g_fused[XN];          // bf16 NHWC
__device__ __align__(16) u16   g_wt[9 * 128 * 128];  // bf16 [pos][co][ci]
__device__ float g_ysum[512];
__device__ float g_se[512];
__device__ int   g_flag[1];

DEVI float ldin(const void* p, int i, int isb) {
    float v;
    if (isb) v = bf2f(((const bf16*)p)[i]);
    else     v = ((const float*)p)[i];
    return v;
}
DEVI void stout(void* p, int i, float v, int isb) {
    if (isb) ((bf16*)p)[i] = f2bf(v);
    else     ((float*)p)[i] = v;
}

// ---------------------------------------------------------------------------
// K0: dtype detect (t_feat + wq) + ysum zero.
__global__ __launch_bounds__(256) void k_detect(
    const void* __restrict__ t, const void* __restrict__ wqp)
{
    __shared__ int bad;
    int tid = threadIdx.x;
    if (tid == 0) bad = 0;
    __syncthreads();
    int mybad = 0;
    for (int i = tid; i < 4096; i += 256) {
        float v = bf2f(((const bf16*)t)[i]);
        if (!(v == v) || fabsf(v) > 64.0f) mybad = 1;
        float u = bf2f(((const bf16*)wqp)[i]);
        if (!(u == u) || fabsf(u) > 64.0f) mybad = 1;
    }
    if (mybad) atomicOr(&bad, 1);
    g_ysum[tid] = 0.f;
    g_ysum[tid + 256] = 0.f;
    __syncthreads();
    if (tid == 0) g_flag[0] = bad ? 0 : 1;
}

// K0b: weight transform w_rd[co][ci][pos] -> g_wt[pos][co][ci] (bf16)
__global__ __launch_bounds__(256) void k_wprep(
    const void* __restrict__ w_rd, u16* __restrict__ gw)
{
    int isb = g_flag[0];
    int i = blockIdx.x * 256 + threadIdx.x;
    if (i >= 9 * 128 * 128) return;
    int pos = i >> 14, rem = i & 16383, co = rem >> 7, ci = rem & 127;
    gw[i] = bfbits(ldin(w_rd, (co * 128 + ci) * 9 + pos, isb));
}

// ---------------------------------------------------------------------------
// K1: q = l2norm(conv1x1(t,wq,bq)), k = l2norm(conv1x1(s,wkc,bkc))
__global__ __launch_bounds__(320) void k_qk(
    const void* __restrict__ t_feat, const void* __restrict__ s_feat,
    const void* __restrict__ wq, const void* __restrict__ bq,
    const void* __restrict__ wkc, const void* __restrict__ bkc,
    float* __restrict__ qout, float* __restrict__ kout)
{
    __shared__ float WST[C_ * CM];   // [c][o]
    __shared__ float BS[CM];
    int isb = g_flag[0];
    int h = blockIdx.x, b = blockIdx.y, which = blockIdx.z;
    const void* in = which ? s_feat : t_feat;
    const void* wm = which ? wkc : wq;
    const void* bb = which ? bkc : bq;
    float* out = which ? kout : qout;
    int tid = threadIdx.x;
    for (int i = tid; i < C_ * CM; i += 320) {
        int o = i >> 7, c = i & 127;
        WST[c * CM + o] = ldin(wm, i, isb);
    }
    if (tid < CM) BS[tid] = ldin(bb, tid, isb);
    __syncthreads();
    int w = tid;
    float acc[CM];
    #pragma unroll
    for (int o = 0; o < CM; o++) acc[o] = BS[o];
    int base = (b * C_) * HW + h * W_ + w;
    for (int c = 0; c < C_; c++) {
        float v = ldin(in, base + c * HW, isb);
        #pragma unroll
        for (int o = 0; o < CM; o++) acc[o] += v * WST[c * CM + o];
    }
    float n = 0.f;
    #pragma unroll
    for (int o = 0; o < CM; o++) n += acc[o] * acc[o];
    float s = 1.0f / fmaxf(sqrtf(n), 1e-12f);
    float* op = out + (b * CM) * HW + h * W_ + w;
    #pragma unroll
    for (int o = 0; o < CM; o++) op[o * HW] = acc[o] * s;
}

// ---------------------------------------------------------------------------
// K2: warp + sim + tanh -> Cv; da = sigmoid(w_da @ [q; mean_d(warped)])
// Spill-free restructure: no q[32] array; peak live = qp+dqa+km = 96 floats.
__global__ __launch_bounds__(320, 3) void k_cost(
    const float* __restrict__ qbuf, const float* __restrict__ kbuf,
    const void* __restrict__ metric, const void* __restrict__ disps,
    const void* __restrict__ directs, const void* __restrict__ alpha_p,
    const void* __restrict__ beta_p, const void* __restrict__ w_da,
    const void* __restrict__ b_da,
    float* __restrict__ Cv, float* __restrict__ da)
{
    __shared__ float KS[CM][W_];
    __shared__ float MS[CM][CM];
    __shared__ float WDA[D_ * 64];
    __shared__ float BDA[D_];
    __shared__ float SH[D_];
    int isb = g_flag[0];
    int h = blockIdx.x, b = blockIdx.y, tid = threadIdx.x, w = tid;
    for (int i = tid; i < CM * CM; i += 320) {
        int c = i >> 5, d = i & 31;
        MS[c][d] = 0.5f * (ldin(metric, c * CM + d, isb) + ldin(metric, d * CM + c, isb));
    }
    for (int i = tid; i < D_ * 64; i += 320) WDA[i] = ldin(w_da, i, isb);
    if (tid < D_) {
        BDA[tid] = ldin(b_da, tid, isb);
        SH[tid] = ldin(disps, tid, isb) * ldin(directs, b, isb) * (float)(W_ - 1);
    }
    const float* kp = kbuf + b * QPLANE + h * W_;
    for (int c = 0; c < CM; c++) KS[c][w] = kp[c * HW + w];
    __syncthreads();

    // Phase A: stream q per channel -> qp (metric proj) + dqa (da q-part).
    float qp[CM], dqa[CM];
    #pragma unroll
    for (int d = 0; d < CM; d++) { qp[d] = 0.f; dqa[d] = 0.f; }
    const float* qpp = qbuf + b * QPLANE + h * W_ + w;
    for (int c = 0; c < CM; c++) {
        float v = qpp[c * HW];
        #pragma unroll
        for (int d = 0; d < CM; d++) qp[d] += v * MS[c][d];
        #pragma unroll
        for (int d = 0; d < D_; d++) dqa[d] += v * WDA[d * 64 + c];
    }

    // Phase B: warp + sim + tanh; km accumulates over d. qp dies after this.
    float km[CM];
    #pragma unroll
    for (int c = 0; c < CM; c++) km[c] = 0.f;
    float alpha = ldin(alpha_p, 0, isb), beta = ldin(beta_p, 0, isb);
    float* cvp = Cv + (b * D_) * HW + h * W_ + w;
    for (int d = 0; d < D_; d++) {
        float px = fminf(fmaxf((float)w + SH[d], 0.f), (float)(W_ - 1));
        int x0 = (int)floorf(px);
        int x1 = min(x0 + 1, W_ - 1);
        float f = px - (float)x0;
        float sim = 0.f;
        #pragma unroll
        for (int c = 0; c < CM; c++) {
            float g0 = KS[c][x0], g1 = KS[c][x1];
            float val = g0 * (1.0f - f) + g1 * f;
            sim += qp[c] * val;
            km[c] += val;
        }
        cvp[d * HW] = tanhf(alpha * sim + beta);
    }

    // Phase C: da from dqa + km (qp dead; live = 64 floats).
    #pragma unroll
    for (int c = 0; c < CM; c++) km[c] *= (1.0f / (float)D_);
    float* dap = da + (b * D_) * HW + h * W_ + w;
    for (int d = 0; d < D_; d++) {
        float s = BDA[d] + dqa[d];
        #pragma unroll
        for (int c = 0; c < CM; c++) s += WDA[d * 64 + 32 + c] * km[c];
        dap[d * HW] = sigmoidf_(s);
    }
}

// ---------------------------------------------------------------------------
// K3: Cf = 3x3 conv(Cv) * da -> softmax over d -> Pf (f32) + P out
__global__ __launch_bounds__(320) void k_cf_softmax(
    const float* __restrict__ Cv, const float* __restrict__ da,
    const void* __restrict__ w_cf, const void* __restrict__ b_cf,
    float* __restrict__ Pf, void* __restrict__ dout)
{
    __shared__ float R[3][322];
    int isb = g_flag[0];
    int h = blockIdx.x, b = blockIdx.y, tid = threadIdx.x, w = tid;
    float wcf[9];
    #pragma unroll
    for (int i = 0; i < 9; i++) wcf[i] = ldin(w_cf, i, isb);
    float bcf = ldin(b_cf, 0, isb);
    float vals[D_];
    for (int d = 0; d < D_; d++) {
        const float* base = Cv + ((b * D_ + d) * H_) * W_;
        #pragma unroll
        for (int r = 0; r < 3; r++) {
            int hh = h + r - 1;
            R[r][w + 1] = (hh >= 0 && hh < H_) ? base[hh * W_ + w] : 0.f;
        }
        if (tid == 0) {
            R[0][0] = R[1][0] = R[2][0] = 0.f;
            R[0][321] = R[1][321] = R[2][321] = 0.f;
        }
        __syncthreads();
        float s = bcf;
        #pragma unroll
        for (int r = 0; r < 3; r++)
            #pragma unroll
            for (int kw = 0; kw < 3; kw++)
                s += R[r][w + kw] * wcf[r * 3 + kw];
        vals[d] = s * da[((b * D_ + d) * H_ + h) * W_ + w];
        __syncthreads();
    }
    float m = vals[0];
    #pragma unroll
    for (int d = 1; d < D_; d++) m = fmaxf(m, vals[d]);
    float sum = 0.f;
    #pragma unroll
    for (int d = 0; d < D_; d++) { vals[d] = expf(vals[d] - m); sum += vals[d]; }
    float inv = 1.0f / sum;
    int o = (b * D_) * HW + h * W_ + w;
    #pragma unroll
    for (int d = 0; d < D_; d++) {
        float p = vals[d] * inv;
        Pf[o + d * HW] = p;
        stout(dout, XN + o + d * HW, p, isb);
    }
}

// ---------------------------------------------------------------------------
// K4: cost = w_ex@P+b_ex; g = sigmoid(w_fg@[t;cost]);
//     fused = g*t+(1-g)*cost  -> g_fused (bf16, NHWC)
__global__ __launch_bounds__(320) void k_fuse(
    const float* __restrict__ Pf, const void* __restrict__ t_feat,
    const void* __restrict__ w_ex, const void* __restrict__ b_ex,
    const void* __restrict__ w_fg, const void* __restrict__ b_fg,
    u16* __restrict__ gf)
{
    __shared__ float WEX[C_ * D_];   // [c][d]
    __shared__ float BEX[C_];
    __shared__ float WFG[2 * C_];
    int isb = g_flag[0];
    int h = blockIdx.x, b = blockIdx.y, tid = threadIdx.x, w = tid;
    for (int i = tid; i < C_ * D_; i += 320) WEX[i] = ldin(w_ex, i, isb);
    if (tid < C_) BEX[tid] = ldin(b_ex, tid, isb);
    for (int i = tid; i < 2 * C_; i += 320) WFG[i] = ldin(w_fg, i, isb);
    __syncthreads();
    float p[D_];
    const float* pp = Pf + (b * D_) * HW + h * W_ + w;
    #pragma unroll
    for (int d = 0; d < D_; d++) p[d] = pp[d * HW];
    int tbase = (b * C_) * HW + h * W_ + w;
    float gacc = ldin(b_fg, 0, isb);
    for (int c = 0; c < C_; c++) {
        float cost = BEX[c];
        #pragma unroll
        for (int d = 0; d < D_; d++) cost += WEX[c * D_ + d] * p[d];
        float tv = ldin(t_feat, tbase + c * HW, isb);
        gacc += WFG[c] * tv + WFG[C_ + c] * cost;
    }
    float g = sigmoidf_(gacc);
    unsigned int* gfo = (unsigned int*)gf + ((b * H_ + h) * W_ + w) * 64;
    for (int c = 0; c < C_; c += 2) {
        float c0 = BEX[c], c1 = BEX[c + 1];
        #pragma unroll
        for (int d = 0; d < D_; d++) {
            c0 += WEX[c * D_ + d] * p[d];
            c1 += WEX[(c + 1) * D_ + d] * p[d];
        }
        float t0 = ldin(t_feat, tbase + c * HW, isb);
        float t1 = ldin(t_feat, tbase + (c + 1) * HW, isb);
        float v0 = g * t0 + (1.0f - g) * c0;
        float v1 = g * t1 + (1.0f - g) * c1;
        gfo[c >> 1] = ((unsigned int)bfbits(v1) << 16) | bfbits(v0);
    }
}

// ---------------------------------------------------------------------------
// K5: x = conv3x3(fused)+b_rd via MFMA implicit GEMM.
// grid (10, 24, 4): 32w x 4h x 128co tile; block 256 (4 waves, 2x2 split).
// Wave (wr,wc): px range wr*64 (4 m-tiles), co range wc*64 (4 n-tiles).
// WS double-buffered with register prefetch (issue-early/write-late);
// XOR swizzle (^ rc&8, u16 units) breaks the 80B-stride r/r+8 bank alias.
// launch_bounds(256,3): reg cap ~170 (64 acc + ~85 arch fits, NO spill).
__global__ __launch_bounds__(256, 3) void k_conv3(
    const u16* __restrict__ gf, const u16* __restrict__ gw,
    const void* __restrict__ b_rd, float* __restrict__ xf)
{
    __shared__ u16 IN[204 * 40];       // 6x34 halo x 32ci, swizzled
    __shared__ u16 WS[2][128 * 40];    // [buf][co][ci], swizzled
    int isb = g_flag[0];
    int tid = threadIdx.x;
    int wave = tid >> 6, lane = tid & 63;
    int wr = wave >> 1, wc = wave & 1;
    int l15 = lane & 15, kq = lane >> 4;
    int w0 = blockIdx.x * 32, h0 = blockIdx.y * 4, b = blockIdx.z;

    f4 acc[4][4];
    #pragma unroll
    for (int mt = 0; mt < 4; mt++)
        #pragma unroll
        for (int nt = 0; nt < 4; nt++) acc[mt][nt] = (f4){0.f, 0.f, 0.f, 0.f};

    float bias[4];
    #pragma unroll
    for (int nt = 0; nt < 4; nt++) bias[nt] = ldin(b_rd, wc * 64 + nt * 16 + l15, isb);

    // prologue: stage WS[0] with (pos=0, cb=0)
    #pragma unroll
    for (int i = 0; i < 2; i++) {
        int s = tid + i * 256, co = s >> 2, q = s & 3;
        *(uint4*)(&WS[0][co * 40 + ((q * 8) ^ (co & 8))]) =
            *(const uint4*)(gw + ((co << 7) + q * 8));
    }

    int step = 0;
    for (int cb = 0; cb < 128; cb += 32) {
        __syncthreads();   // prev cb's readers of IN are done
        for (int s = tid; s < 204 * 4; s += 256) {
            int p = s >> 2, q = s & 3;
            int hp = p / 34, wp = p - hp * 34;
            int hg = h0 - 1 + hp, wg = w0 - 1 + wp;
            uint4 v = make_uint4(0u, 0u, 0u, 0u);
            if (hg >= 0 && hg < H_ && wg >= 0 && wg < W_)
                v = *(const uint4*)(gf + ((((b * H_ + hg) * W_ + wg) << 7) + cb + q * 8));
            *(uint4*)(&IN[p * 40 + ((q * 8) ^ (p & 8))]) = v;
        }
        __syncthreads();   // IN + WS[step&1] visible
        for (int pos = 0; pos < 9; pos++, step++) {
            int cur = step & 1;
            // prefetch next step's weights into regs (issue-early)
            uint4 wreg0, wreg1;
            int have = (step < 35);
            int pn = (pos == 8) ? 0 : pos + 1;
            int cbn = (pos == 8) ? cb + 32 : cb;
            if (have) {
                int co0 = tid >> 2, q0 = tid & 3;
                wreg0 = *(const uint4*)(gw + (((pn * 128 + co0) << 7) + cbn + q0 * 8));
                int s1 = tid + 256, co1 = s1 >> 2, q1 = s1 & 3;
                wreg1 = *(const uint4*)(gw + (((pn * 128 + co1) << 7) + cbn + q1 * 8));
            }
            // compute pos from WS[cur] / IN
            int kh = pos / 3, kw = pos - kh * 3;
            bf16x8 bfr[4];
            #pragma unroll
            for (int nt = 0; nt < 4; nt++) {
                int co = wc * 64 + nt * 16 + l15;
                bfr[nt] = *(bf16x8*)(&WS[cur][co * 40 + ((kq * 8) ^ (co & 8))]);
            }
            #pragma unroll
            for (int mt = 0; mt < 4; mt++) {
                int px = wr * 64 + mt * 16 + l15;
                int rc = ((px >> 5) + kh) * 34 + (px & 31) + kw;
                bf16x8 afr = *(bf16x8*)(&IN[rc * 40 + ((kq * 8) ^ (rc & 8))]);
                #pragma unroll
                for (int nt = 0; nt < 4; nt++)
                    acc[mt][nt] = __builtin_amdgcn_mfma_f32_16x16x32_bf16(
                        afr, bfr[nt], acc[mt][nt], 0, 0, 0);
            }
            // write-late: stage prefetched weights into the other buffer
            if (have) {
                int co0 = tid >> 2, q0 = tid & 3;
                *(uint4*)(&WS[cur ^ 1][co0 * 40 + ((q0 * 8) ^ (co0 & 8))]) = wreg0;
                int s1 = tid + 256, co1 = s1 >> 2, q1 = s1 & 3;
                *(uint4*)(&WS[cur ^ 1][co1 * 40 + ((q1 * 8) ^ (co1 & 8))]) = wreg1;
            }
            __syncthreads();
        }
    }
    // epilogue: bias, store x (f32 NCHW), SE partial sums
    #pragma unroll
    for (int nt = 0; nt < 4; nt++) {
        int co = wc * 64 + nt * 16 + l15;
        float ps = 0.f;
        #pragma unroll
        for (int mt = 0; mt < 4; mt++) {
            #pragma unroll
            for (int r = 0; r < 4; r++) {
                int px = wr * 64 + mt * 16 + kq * 4 + r;
                float v = acc[mt][nt][r] + bias[nt];
                ps += v;
                xf[((b * C_ + co) * H_ + h0 + (px >> 5)) * W_ + w0 + (px & 31)] = v;
            }
        }
        ps += __shfl_xor(ps, 16);
        ps += __shfl_xor(ps, 32);
        if (lane < 16) atomicAdd(&g_ysum[b * C_ + co], ps);
    }
}

// ---------------------------------------------------------------------------
// K6: SE scale per (b,c)
__global__ __launch_bounds__(512) void k_se(
    const void* __restrict__ w_se1, const void* __restrict__ w_se2)
{
    __shared__ float YM[B_ * C_];
    __shared__ float Y1[B_ * 8];
    int isb = g_flag[0];
    int tid = threadIdx.x;
    YM[tid] = g_ysum[tid] * (1.0f / (float)HW);
    __syncthreads();
    if (tid < 32) {
        int b = tid >> 3, j = tid & 7;
        float s = 0.f;
        for (int c = 0; c < C_; c++) s += YM[b * C_ + c] * ldin(w_se1, j * C_ + c, isb);
        Y1[tid] = fmaxf(s, 0.f);
    }
    __syncthreads();
    int b = tid >> 7, c = tid & 127;
    float s = 0.f;
    #pragma unroll
    for (int j = 0; j < 8; j++) s += Y1[b * 8 + j] * ldin(w_se2, c * 8 + j, isb);
    g_se[tid] = sigmoidf_(s);
}

// K7: out_x = elu(xf32 * se), in detected output dtype
__global__ __launch_bounds__(256) void k_elu(
    const float* __restrict__ xf, void* __restrict__ dout)
{
    int isb = g_flag[0];
    int idx = blockIdx.x * 256 + threadIdx.x;
    if (idx >= XN) return;
    int plane = idx / HW;
    float v = xf[idx] * g_se[plane];
    stout(dout, idx, v > 0.f ? v : expm1f(v), isb);
}

// ---------------------------------------------------------------------------
extern "C" void kernel_launch(void* const* d_in, const int* in_sizes, int n_in,
                              void* d_out, int out_size, void* d_ws, size_t ws_size,
                              hipStream_t stream)
{
    const void* t_feat  = d_in[0];
    const void* s_feat  = d_in[1];
    const void* directs = d_in[2];
    /* d_in[3] image_shape: unused */
    const void* disps   = d_in[4];
    const void* wq      = d_in[5];
    const void* bq      = d_in[6];
    const void* wkc     = d_in[7];
    const void* bkc     = d_in[8];
    const void* metric  = d_in[9];
    const void* alpha   = d_in[10];
    const void* beta    = d_in[11];
    const void* w_cf    = d_in[12];
    const void* b_cf    = d_in[13];
    const void* w_da    = d_in[14];
    const void* b_da    = d_in[15];
    const void* w_ex    = d_in[16];
    const void* b_ex    = d_in[17];
    const void* w_fg    = d_in[18];
    const void* b_fg    = d_in[19];
    const void* w_rd    = d_in[20];
    const void* b_rd    = d_in[21];
    const void* w_se1   = d_in[22];
    const void* w_se2   = d_in[23];
    (void)in_sizes; (void)n_in; (void)out_size; (void)d_ws; (void)ws_size;

    float* base = nullptr;
    (void)hipGetSymbolAddress((void**)&base, HIP_SYMBOL(g_scratch));
    u16* gf = nullptr;
    (void)hipGetSymbolAddress((void**)&gf, HIP_SYMBOL(g_fused));
    u16* gw = nullptr;
    (void)hipGetSymbolAddress((void**)&gw, HIP_SYMBOL(g_wt));
    float* qb = base;
    float* kb = base + PLN;
    float* Cv = base + 2 * PLN;
    float* da = base + 3 * PLN;
    float* Pf = base + 4 * PLN;
    float* xf = base + 4 * PLN;      // overlays Pf (dead after k_fuse)

    k_detect<<<1, 256, 0, stream>>>(t_feat, wq);
    k_wprep<<<576, 256, 0, stream>>>(w_rd, gw);
    k_qk<<<dim3(H_, B_, 2), 320, 0, stream>>>(t_feat, s_feat, wq, bq, wkc, bkc, qb, kb);
    k_cost<<<dim3(H_, B_), 320, 0, stream>>>(qb, kb, metric, disps, directs,
                                             alpha, beta, w_da, b_da, Cv, da);
    k_cf_softmax<<<dim3(H_, B_), 320, 0, stream>>>(Cv, da, w_cf, b_cf, Pf, d_out);
    k_fuse<<<dim3(H_, B_), 320, 0, stream>>>(Pf, t_feat, w_ex, b_ex, w_fg, b_fg, gf);
    k_conv3<<<dim3(10, 24, 4), 256, 0, stream>>>(gf, gw, b_rd, xf);
    k_se<<<1, 512, 0, stream>>>(w_se1, w_se2);
    k_elu<<<(XN + 255) / 256, 256, 0, stream>>>(xf, d_out);
}

// Round 6
// 631.486 us; speedup vs baseline: 1.1061x; 1.0680x over previous
//
#include <hip/hip_runtime.h>
#include <hip/hip_bf16.h>
#include <math.h>

// HMF block, round 10:
//  - k_conv3: REVERT to verified round-7 2-wave version (128 µs, clean
//    63/78 MB traffic). Rounds 8-9's 4-wave dbuf/prefetch/swizzle was a
//    net regression (141-169 µs, residual spill, occupancy 25% not 37%).
//  - k_fuse: algebraic halving — gacc's Σc WFG2[c]*cost[c] folded to
//    pre0 + Σd p[d]*wpre[d] with wpre[d]=Σc WFG2[c]*WEX[c][d] computed
//    once per block in LDS. Removes 4096 FMA/thread (half the kernel).
// Everything else identical to verified round 7/9 pipeline.

typedef __hip_bfloat16 bf16;
typedef unsigned short u16;
typedef __attribute__((ext_vector_type(8))) __bf16 bf16x8;
typedef __attribute__((ext_vector_type(4))) float f4;

#define DEVI static __device__ __forceinline__
DEVI float bf2f(bf16 x) { return __bfloat162float(x); }
DEVI bf16  f2bf(float x) { return __float2bfloat16(x); }
DEVI u16 bfbits(float x) { bf16 h = f2bf(x); return *(u16*)&h; }
DEVI float sigmoidf_(float x) { return 1.0f / (1.0f + expf(-x)); }

constexpr int B_ = 4, C_ = 128, H_ = 96, W_ = 320, CM = 32, D_ = 32;
constexpr int HW = H_ * W_;              // 30720
constexpr int QPLANE = CM * HW;          // 983040
constexpr int XN = B_ * C_ * HW;         // 15728640
constexpr int PLN = B_ * D_ * HW;        // 3932160

// scratch slots (floats): q=0 | k=1 | Cv=2 | da=3 | Pf=4 ; xf overlays 4-7.
__device__ __align__(16) float g_scratch[8 * PLN];
__device__ __align__(16) u16   g_fused[XN];          // bf16 NHWC
__device__ __align__(16) u16   g_wt[9 * 128 * 128];  // bf16 [pos][co][ci]
__device__ float g_ysum[512];
__device__ float g_se[512];
__device__ int   g_flag[1];

DEVI float ldin(const void* p, int i, int isb) {
    float v;
    if (isb) v = bf2f(((const bf16*)p)[i]);
    else     v = ((const float*)p)[i];
    return v;
}
DEVI void stout(void* p, int i, float v, int isb) {
    if (isb) ((bf16*)p)[i] = f2bf(v);
    else     ((float*)p)[i] = v;
}

// ---------------------------------------------------------------------------
// K0: dtype detect (t_feat + wq) + ysum zero.
__global__ __launch_bounds__(256) void k_detect(
    const void* __restrict__ t, const void* __restrict__ wqp)
{
    __shared__ int bad;
    int tid = threadIdx.x;
    if (tid == 0) bad = 0;
    __syncthreads();
    int mybad = 0;
    for (int i = tid; i < 4096; i += 256) {
        float v = bf2f(((const bf16*)t)[i]);
        if (!(v == v) || fabsf(v) > 64.0f) mybad = 1;
        float u = bf2f(((const bf16*)wqp)[i]);
        if (!(u == u) || fabsf(u) > 64.0f) mybad = 1;
    }
    if (mybad) atomicOr(&bad, 1);
    g_ysum[tid] = 0.f;
    g_ysum[tid + 256] = 0.f;
    __syncthreads();
    if (tid == 0) g_flag[0] = bad ? 0 : 1;
}

// K0b: weight transform w_rd[co][ci][pos] -> g_wt[pos][co][ci] (bf16)
__global__ __launch_bounds__(256) void k_wprep(
    const void* __restrict__ w_rd, u16* __restrict__ gw)
{
    int isb = g_flag[0];
    int i = blockIdx.x * 256 + threadIdx.x;
    if (i >= 9 * 128 * 128) return;
    int pos = i >> 14, rem = i & 16383, co = rem >> 7, ci = rem & 127;
    gw[i] = bfbits(ldin(w_rd, (co * 128 + ci) * 9 + pos, isb));
}

// ---------------------------------------------------------------------------
// K1: q = l2norm(conv1x1(t,wq,bq)), k = l2norm(conv1x1(s,wkc,bkc))
__global__ __launch_bounds__(320) void k_qk(
    const void* __restrict__ t_feat, const void* __restrict__ s_feat,
    const void* __restrict__ wq, const void* __restrict__ bq,
    const void* __restrict__ wkc, const void* __restrict__ bkc,
    float* __restrict__ qout, float* __restrict__ kout)
{
    __shared__ float WST[C_ * CM];   // [c][o]
    __shared__ float BS[CM];
    int isb = g_flag[0];
    int h = blockIdx.x, b = blockIdx.y, which = blockIdx.z;
    const void* in = which ? s_feat : t_feat;
    const void* wm = which ? wkc : wq;
    const void* bb = which ? bkc : bq;
    float* out = which ? kout : qout;
    int tid = threadIdx.x;
    for (int i = tid; i < C_ * CM; i += 320) {
        int o = i >> 7, c = i & 127;
        WST[c * CM + o] = ldin(wm, i, isb);
    }
    if (tid < CM) BS[tid] = ldin(bb, tid, isb);
    __syncthreads();
    int w = tid;
    float acc[CM];
    #pragma unroll
    for (int o = 0; o < CM; o++) acc[o] = BS[o];
    int base = (b * C_) * HW + h * W_ + w;
    for (int c = 0; c < C_; c++) {
        float v = ldin(in, base + c * HW, isb);
        #pragma unroll
        for (int o = 0; o < CM; o++) acc[o] += v * WST[c * CM + o];
    }
    float n = 0.f;
    #pragma unroll
    for (int o = 0; o < CM; o++) n += acc[o] * acc[o];
    float s = 1.0f / fmaxf(sqrtf(n), 1e-12f);
    float* op = out + (b * CM) * HW + h * W_ + w;
    #pragma unroll
    for (int o = 0; o < CM; o++) op[o * HW] = acc[o] * s;
}

// ---------------------------------------------------------------------------
// K2: warp + sim + tanh -> Cv; da = sigmoid(w_da @ [q; mean_d(warped)])
// Spill-free restructure: no q[32] array; peak live = qp+dqa+km = 96 floats.
__global__ __launch_bounds__(320, 3) void k_cost(
    const float* __restrict__ qbuf, const float* __restrict__ kbuf,
    const void* __restrict__ metric, const void* __restrict__ disps,
    const void* __restrict__ directs, const void* __restrict__ alpha_p,
    const void* __restrict__ beta_p, const void* __restrict__ w_da,
    const void* __restrict__ b_da,
    float* __restrict__ Cv, float* __restrict__ da)
{
    __shared__ float KS[CM][W_];
    __shared__ float MS[CM][CM];
    __shared__ float WDA[D_ * 64];
    __shared__ float BDA[D_];
    __shared__ float SH[D_];
    int isb = g_flag[0];
    int h = blockIdx.x, b = blockIdx.y, tid = threadIdx.x, w = tid;
    for (int i = tid; i < CM * CM; i += 320) {
        int c = i >> 5, d = i & 31;
        MS[c][d] = 0.5f * (ldin(metric, c * CM + d, isb) + ldin(metric, d * CM + c, isb));
    }
    for (int i = tid; i < D_ * 64; i += 320) WDA[i] = ldin(w_da, i, isb);
    if (tid < D_) {
        BDA[tid] = ldin(b_da, tid, isb);
        SH[tid] = ldin(disps, tid, isb) * ldin(directs, b, isb) * (float)(W_ - 1);
    }
    const float* kp = kbuf + b * QPLANE + h * W_;
    for (int c = 0; c < CM; c++) KS[c][w] = kp[c * HW + w];
    __syncthreads();

    // Phase A: stream q per channel -> qp (metric proj) + dqa (da q-part).
    float qp[CM], dqa[CM];
    #pragma unroll
    for (int d = 0; d < CM; d++) { qp[d] = 0.f; dqa[d] = 0.f; }
    const float* qpp = qbuf + b * QPLANE + h * W_ + w;
    for (int c = 0; c < CM; c++) {
        float v = qpp[c * HW];
        #pragma unroll
        for (int d = 0; d < CM; d++) qp[d] += v * MS[c][d];
        #pragma unroll
        for (int d = 0; d < D_; d++) dqa[d] += v * WDA[d * 64 + c];
    }

    // Phase B: warp + sim + tanh; km accumulates over d. qp dies after this.
    float km[CM];
    #pragma unroll
    for (int c = 0; c < CM; c++) km[c] = 0.f;
    float alpha = ldin(alpha_p, 0, isb), beta = ldin(beta_p, 0, isb);
    float* cvp = Cv + (b * D_) * HW + h * W_ + w;
    for (int d = 0; d < D_; d++) {
        float px = fminf(fmaxf((float)w + SH[d], 0.f), (float)(W_ - 1));
        int x0 = (int)floorf(px);
        int x1 = min(x0 + 1, W_ - 1);
        float f = px - (float)x0;
        float sim = 0.f;
        #pragma unroll
        for (int c = 0; c < CM; c++) {
            float g0 = KS[c][x0], g1 = KS[c][x1];
            float val = g0 * (1.0f - f) + g1 * f;
            sim += qp[c] * val;
            km[c] += val;
        }
        cvp[d * HW] = tanhf(alpha * sim + beta);
    }

    // Phase C: da from dqa + km (qp dead; live = 64 floats).
    #pragma unroll
    for (int c = 0; c < CM; c++) km[c] *= (1.0f / (float)D_);
    float* dap = da + (b * D_) * HW + h * W_ + w;
    for (int d = 0; d < D_; d++) {
        float s = BDA[d] + dqa[d];
        #pragma unroll
        for (int c = 0; c < CM; c++) s += WDA[d * 64 + 32 + c] * km[c];
        dap[d * HW] = sigmoidf_(s);
    }
}

// ---------------------------------------------------------------------------
// K3: Cf = 3x3 conv(Cv) * da -> softmax over d -> Pf (f32) + P out
__global__ __launch_bounds__(320) void k_cf_softmax(
    const float* __restrict__ Cv, const float* __restrict__ da,
    const void* __restrict__ w_cf, const void* __restrict__ b_cf,
    float* __restrict__ Pf, void* __restrict__ dout)
{
    __shared__ float R[3][322];
    int isb = g_flag[0];
    int h = blockIdx.x, b = blockIdx.y, tid = threadIdx.x, w = tid;
    float wcf[9];
    #pragma unroll
    for (int i = 0; i < 9; i++) wcf[i] = ldin(w_cf, i, isb);
    float bcf = ldin(b_cf, 0, isb);
    float vals[D_];
    for (int d = 0; d < D_; d++) {
        const float* base = Cv + ((b * D_ + d) * H_) * W_;
        #pragma unroll
        for (int r = 0; r < 3; r++) {
            int hh = h + r - 1;
            R[r][w + 1] = (hh >= 0 && hh < H_) ? base[hh * W_ + w] : 0.f;
        }
        if (tid == 0) {
            R[0][0] = R[1][0] = R[2][0] = 0.f;
            R[0][321] = R[1][321] = R[2][321] = 0.f;
        }
        __syncthreads();
        float s = bcf;
        #pragma unroll
        for (int r = 0; r < 3; r++)
            #pragma unroll
            for (int kw = 0; kw < 3; kw++)
                s += R[r][w + kw] * wcf[r * 3 + kw];
        vals[d] = s * da[((b * D_ + d) * H_ + h) * W_ + w];
        __syncthreads();
    }
    float m = vals[0];
    #pragma unroll
    for (int d = 1; d < D_; d++) m = fmaxf(m, vals[d]);
    float sum = 0.f;
    #pragma unroll
    for (int d = 0; d < D_; d++) { vals[d] = expf(vals[d] - m); sum += vals[d]; }
    float inv = 1.0f / sum;
    int o = (b * D_) * HW + h * W_ + w;
    #pragma unroll
    for (int d = 0; d < D_; d++) {
        float p = vals[d] * inv;
        Pf[o + d * HW] = p;
        stout(dout, XN + o + d * HW, p, isb);
    }
}

// ---------------------------------------------------------------------------
// K4: cost = w_ex@P+b_ex; g = sigmoid(w_fg@[t;cost]);
//     fused = g*t+(1-g)*cost  -> g_fused (bf16, NHWC)
// gacc's cost-term folded: Sc WFG2[c]*cost[c] = pre0 + Sd p[d]*wpre[d].
__global__ __launch_bounds__(320) void k_fuse(
    const float* __restrict__ Pf, const void* __restrict__ t_feat,
    const void* __restrict__ w_ex, const void* __restrict__ b_ex,
    const void* __restrict__ w_fg, const void* __restrict__ b_fg,
    u16* __restrict__ gf)
{
    __shared__ float WEX[C_ * D_];   // [c][d]
    __shared__ float BEX[C_];
    __shared__ float WFG[2 * C_];
    __shared__ float WPRE[D_ + 1];   // wpre[d] = Sc WFG2[c]*WEX[c][d]; [D_]=Sc WFG2[c]*BEX[c]
    int isb = g_flag[0];
    int h = blockIdx.x, b = blockIdx.y, tid = threadIdx.x, w = tid;
    for (int i = tid; i < C_ * D_; i += 320) WEX[i] = ldin(w_ex, i, isb);
    if (tid < C_) BEX[tid] = ldin(b_ex, tid, isb);
    for (int i = tid; i < 2 * C_; i += 320) WFG[i] = ldin(w_fg, i, isb);
    __syncthreads();
    if (tid < D_) {
        float s = 0.f;
        for (int c = 0; c < C_; c++) s += WFG[C_ + c] * WEX[c * D_ + tid];
        WPRE[tid] = s;
    } else if (tid == D_) {
        float s = 0.f;
        for (int c = 0; c < C_; c++) s += WFG[C_ + c] * BEX[c];
        WPRE[D_] = s;
    }
    __syncthreads();
    float p[D_];
    const float* pp = Pf + (b * D_) * HW + h * W_ + w;
    #pragma unroll
    for (int d = 0; d < D_; d++) p[d] = pp[d * HW];
    int tbase = (b * C_) * HW + h * W_ + w;
    float gacc = ldin(b_fg, 0, isb) + WPRE[D_];
    #pragma unroll
    for (int d = 0; d < D_; d++) gacc += WPRE[d] * p[d];
    for (int c = 0; c < C_; c++)
        gacc += WFG[c] * ldin(t_feat, tbase + c * HW, isb);
    float g = sigmoidf_(gacc);
    unsigned int* gfo = (unsigned int*)gf + ((b * H_ + h) * W_ + w) * 64;
    for (int c = 0; c < C_; c += 2) {
        float c0 = BEX[c], c1 = BEX[c + 1];
        #pragma unroll
        for (int d = 0; d < D_; d++) {
            c0 += WEX[c * D_ + d] * p[d];
            c1 += WEX[(c + 1) * D_ + d] * p[d];
        }
        float t0 = ldin(t_feat, tbase + c * HW, isb);
        float t1 = ldin(t_feat, tbase + (c + 1) * HW, isb);
        float v0 = g * t0 + (1.0f - g) * c0;
        float v1 = g * t1 + (1.0f - g) * c1;
        gfo[c >> 1] = ((unsigned int)bfbits(v1) << 16) | bfbits(v0);
    }
}

// ---------------------------------------------------------------------------
// K5: x = conv3x3(fused)+b_rd via MFMA implicit GEMM. (verified round-7 ver.)
// grid (10, 24, 4): 32w x 4h x 128co tile; block 128 (2 waves).
// Wave tile: 64 px x 128 co = 4 m-tiles x 8 n-tiles of 16x16x32 bf16 MFMA.
// LDS: input halo 6x34x32ci (pad->40) + weights 128co x 32ci (pad->40).
__global__ __launch_bounds__(128, 2) void k_conv3(
    const u16* __restrict__ gf, const u16* __restrict__ gw,
    const void* __restrict__ b_rd, float* __restrict__ xf)
{
    __shared__ u16 IN[6 * 34 * 40];
    __shared__ u16 WS[128 * 40];
    int isb = g_flag[0];
    int tid = threadIdx.x;
    int wave = tid >> 6, lane = tid & 63;
    int l15 = lane & 15, kq = lane >> 4;
    int w0 = blockIdx.x * 32, h0 = blockIdx.y * 4, b = blockIdx.z;

    f4 acc[4][8];
    #pragma unroll
    for (int mt = 0; mt < 4; mt++)
        #pragma unroll
        for (int nt = 0; nt < 8; nt++) acc[mt][nt] = (f4){0.f, 0.f, 0.f, 0.f};

    float bias[8];
    #pragma unroll
    for (int nt = 0; nt < 8; nt++) bias[nt] = ldin(b_rd, nt * 16 + l15, isb);

    for (int cb = 0; cb < 128; cb += 32) {
        __syncthreads();
        // stage input halo chunk: 6 rows x 34 cols x 32 ci (16B per thread-item)
        for (int s = tid; s < 204 * 4; s += 128) {
            int p = s >> 2, q = s & 3;
            int hp = p / 34, wp = p - hp * 34;
            int hg = h0 - 1 + hp, wg = w0 - 1 + wp;
            uint4 v = make_uint4(0u, 0u, 0u, 0u);
            if (hg >= 0 && hg < H_ && wg >= 0 && wg < W_)
                v = *(const uint4*)(gf + ((((b * H_ + hg) * W_ + wg) << 7) + cb + q * 8));
            *(uint4*)(&IN[(hp * 34 + wp) * 40 + q * 8]) = v;
        }
        for (int pos = 0; pos < 9; pos++) {
            __syncthreads();
            for (int s = tid; s < 128 * 4; s += 128) {
                int co = s >> 2, q = s & 3;
                *(uint4*)(&WS[co * 40 + q * 8]) =
                    *(const uint4*)(gw + (((pos * 128 + co) << 7) + cb + q * 8));
            }
            __syncthreads();
            int kh = pos / 3, kw = pos - kh * 3;
            bf16x8 bfr[8];
            #pragma unroll
            for (int nt = 0; nt < 8; nt++)
                bfr[nt] = *(bf16x8*)(&WS[(nt * 16 + l15) * 40 + kq * 8]);
            #pragma unroll
            for (int mt = 0; mt < 4; mt++) {
                int px = wave * 64 + mt * 16 + l15;
                int row = (px >> 5) + kh, col = (px & 31) + kw;
                bf16x8 afr = *(bf16x8*)(&IN[(row * 34 + col) * 40 + kq * 8]);
                #pragma unroll
                for (int nt = 0; nt < 8; nt++)
                    acc[mt][nt] = __builtin_amdgcn_mfma_f32_16x16x32_bf16(
                        afr, bfr[nt], acc[mt][nt], 0, 0, 0);
            }
        }
    }
    // epilogue: bias, store x (f32 NCHW), SE partial sums
    #pragma unroll
    for (int nt = 0; nt < 8; nt++) {
        int co = nt * 16 + l15;
        float ps = 0.f;
        #pragma unroll
        for (int mt = 0; mt < 4; mt++) {
            #pragma unroll
            for (int r = 0; r < 4; r++) {
                int px = wave * 64 + mt * 16 + kq * 4 + r;
                float v = acc[mt][nt][r] + bias[nt];
                ps += v;
                xf[((b * C_ + co) * H_ + h0 + (px >> 5)) * W_ + w0 + (px & 31)] = v;
            }
        }
        ps += __shfl_xor(ps, 16);
        ps += __shfl_xor(ps, 32);
        if (lane < 16) atomicAdd(&g_ysum[b * C_ + co], ps);
    }
}

// ---------------------------------------------------------------------------
// K6: SE scale per (b,c)
__global__ __launch_bounds__(512) void k_se(
    const void* __restrict__ w_se1, const void* __restrict__ w_se2)
{
    __shared__ float YM[B_ * C_];
    __shared__ float Y1[B_ * 8];
    int isb = g_flag[0];
    int tid = threadIdx.x;
    YM[tid] = g_ysum[tid] * (1.0f / (float)HW);
    __syncthreads();
    if (tid < 32) {
        int b = tid >> 3, j = tid & 7;
        float s = 0.f;
        for (int c = 0; c < C_; c++) s += YM[b * C_ + c] * ldin(w_se1, j * C_ + c, isb);
        Y1[tid] = fmaxf(s, 0.f);
    }
    __syncthreads();
    int b = tid >> 7, c = tid & 127;
    float s = 0.f;
    #pragma unroll
    for (int j = 0; j < 8; j++) s += Y1[b * 8 + j] * ldin(w_se2, c * 8 + j, isb);
    g_se[tid] = sigmoidf_(s);
}

// K7: out_x = elu(xf32 * se), in detected output dtype
__global__ __launch_bounds__(256) void k_elu(
    const float* __restrict__ xf, void* __restrict__ dout)
{
    int isb = g_flag[0];
    int idx = blockIdx.x * 256 + threadIdx.x;
    if (idx >= XN) return;
    int plane = idx / HW;
    float v = xf[idx] * g_se[plane];
    stout(dout, idx, v > 0.f ? v : expm1f(v), isb);
}

// ---------------------------------------------------------------------------
extern "C" void kernel_launch(void* const* d_in, const int* in_sizes, int n_in,
                              void* d_out, int out_size, void* d_ws, size_t ws_size,
                              hipStream_t stream)
{
    const void* t_feat  = d_in[0];
    const void* s_feat  = d_in[1];
    const void* directs = d_in[2];
    /* d_in[3] image_shape: unused */
    const void* disps   = d_in[4];
    const void* wq      = d_in[5];
    const void* bq      = d_in[6];
    const void* wkc     = d_in[7];
    const void* bkc     = d_in[8];
    const void* metric  = d_in[9];
    const void* alpha   = d_in[10];
    const void* beta    = d_in[11];
    const void* w_cf    = d_in[12];
    const void* b_cf    = d_in[13];
    const void* w_da    = d_in[14];
    const void* b_da    = d_in[15];
    const void* w_ex    = d_in[16];
    const void* b_ex    = d_in[17];
    const void* w_fg    = d_in[18];
    const void* b_fg    = d_in[19];
    const void* w_rd    = d_in[20];
    const void* b_rd    = d_in[21];
    const void* w_se1   = d_in[22];
    const void* w_se2   = d_in[23];
    (void)in_sizes; (void)n_in; (void)out_size; (void)d_ws; (void)ws_size;

    float* base = nullptr;
    (void)hipGetSymbolAddress((void**)&base, HIP_SYMBOL(g_scratch));
    u16* gf = nullptr;
    (void)hipGetSymbolAddress((void**)&gf, HIP_SYMBOL(g_fused));
    u16* gw = nullptr;
    (void)hipGetSymbolAddress((void**)&gw, HIP_SYMBOL(g_wt));
    float* qb = base;
    float* kb = base + PLN;
    float* Cv = base + 2 * PLN;
    float* da = base + 3 * PLN;
    float* Pf = base + 4 * PLN;
    float* xf = base + 4 * PLN;      // overlays Pf (dead after k_fuse)

    k_detect<<<1, 256, 0, stream>>>(t_feat, wq);
    k_wprep<<<576, 256, 0, stream>>>(w_rd, gw);
    k_qk<<<dim3(H_, B_, 2), 320, 0, stream>>>(t_feat, s_feat, wq, bq, wkc, bkc, qb, kb);
    k_cost<<<dim3(H_, B_), 320, 0, stream>>>(qb, kb, metric, disps, directs,
                                             alpha, beta, w_da, b_da, Cv, da);
    k_cf_softmax<<<dim3(H_, B_), 320, 0, stream>>>(Cv, da, w_cf, b_cf, Pf, d_out);
    k_fuse<<<dim3(H_, B_), 320, 0, stream>>>(Pf, t_feat, w_ex, b_ex, w_fg, b_fg, gf);
    k_conv3<<<dim3(10, 24, 4), 128, 0, stream>>>(gf, gw, b_rd, xf);
    k_se<<<1, 512, 0, stream>>>(w_se1, w_se2);
    k_elu<<<(XN + 255) / 256, 256, 0, stream>>>(xf, d_out);
}

// Round 7
// 622.490 us; speedup vs baseline: 1.1221x; 1.0145x over previous
//
#include <hip/hip_runtime.h>
#include <hip/hip_bf16.h>
#include <math.h>

// HMF block, round 11 (baseline 631 µs, k_conv3=121 top):
//  - k_cf_softmax + k_fuse FUSED into k_cfp: the old cf_softmax ran 64
//    barriers/block (2 per d) and wrote Pf (63 MB) solely for k_fuse to
//    re-read (63 MB). k_cfp computes the 3x3 conv by direct L2 reads of
//    Cv (no staging, no per-d barriers), keeps p[32] in registers through
//    softmax, and feeds the fuse stage directly. Pf buffer eliminated.
//    Tap order preserved (OOB skip == +0), so numerics identical.
//  - k_elu vectorized x4 (float4 in, packed bf16x2 out).
// Everything else identical to verified round 10.

typedef __hip_bfloat16 bf16;
typedef unsigned short u16;
typedef __attribute__((ext_vector_type(8))) __bf16 bf16x8;
typedef __attribute__((ext_vector_type(4))) float f4;

#define DEVI static __device__ __forceinline__
DEVI float bf2f(bf16 x) { return __bfloat162float(x); }
DEVI bf16  f2bf(float x) { return __float2bfloat16(x); }
DEVI u16 bfbits(float x) { bf16 h = f2bf(x); return *(u16*)&h; }
DEVI float sigmoidf_(float x) { return 1.0f / (1.0f + expf(-x)); }

constexpr int B_ = 4, C_ = 128, H_ = 96, W_ = 320, CM = 32, D_ = 32;
constexpr int HW = H_ * W_;              // 30720
constexpr int QPLANE = CM * HW;          // 983040
constexpr int XN = B_ * C_ * HW;         // 15728640
constexpr int PLN = B_ * D_ * HW;        // 3932160

// scratch slots (floats): q=0 | k=1 | Cv=2 | da=3 ; xf overlays 4-7.
__device__ __align__(16) float g_scratch[8 * PLN];
__device__ __align__(16) u16   g_fused[XN];          // bf16 NHWC
__device__ __align__(16) u16   g_wt[9 * 128 * 128];  // bf16 [pos][co][ci]
__device__ float g_ysum[512];
__device__ float g_se[512];
__device__ int   g_flag[1];

DEVI float ldin(const void* p, int i, int isb) {
    float v;
    if (isb) v = bf2f(((const bf16*)p)[i]);
    else     v = ((const float*)p)[i];
    return v;
}
DEVI void stout(void* p, int i, float v, int isb) {
    if (isb) ((bf16*)p)[i] = f2bf(v);
    else     ((float*)p)[i] = v;
}

// ---------------------------------------------------------------------------
// K0: dtype detect (t_feat + wq) + ysum zero.
__global__ __launch_bounds__(256) void k_detect(
    const void* __restrict__ t, const void* __restrict__ wqp)
{
    __shared__ int bad;
    int tid = threadIdx.x;
    if (tid == 0) bad = 0;
    __syncthreads();
    int mybad = 0;
    for (int i = tid; i < 4096; i += 256) {
        float v = bf2f(((const bf16*)t)[i]);
        if (!(v == v) || fabsf(v) > 64.0f) mybad = 1;
        float u = bf2f(((const bf16*)wqp)[i]);
        if (!(u == u) || fabsf(u) > 64.0f) mybad = 1;
    }
    if (mybad) atomicOr(&bad, 1);
    g_ysum[tid] = 0.f;
    g_ysum[tid + 256] = 0.f;
    __syncthreads();
    if (tid == 0) g_flag[0] = bad ? 0 : 1;
}

// K0b: weight transform w_rd[co][ci][pos] -> g_wt[pos][co][ci] (bf16)
__global__ __launch_bounds__(256) void k_wprep(
    const void* __restrict__ w_rd, u16* __restrict__ gw)
{
    int isb = g_flag[0];
    int i = blockIdx.x * 256 + threadIdx.x;
    if (i >= 9 * 128 * 128) return;
    int pos = i >> 14, rem = i & 16383, co = rem >> 7, ci = rem & 127;
    gw[i] = bfbits(ldin(w_rd, (co * 128 + ci) * 9 + pos, isb));
}

// ---------------------------------------------------------------------------
// K1: q = l2norm(conv1x1(t,wq,bq)), k = l2norm(conv1x1(s,wkc,bkc))
__global__ __launch_bounds__(320) void k_qk(
    const void* __restrict__ t_feat, const void* __restrict__ s_feat,
    const void* __restrict__ wq, const void* __restrict__ bq,
    const void* __restrict__ wkc, const void* __restrict__ bkc,
    float* __restrict__ qout, float* __restrict__ kout)
{
    __shared__ float WST[C_ * CM];   // [c][o]
    __shared__ float BS[CM];
    int isb = g_flag[0];
    int h = blockIdx.x, b = blockIdx.y, which = blockIdx.z;
    const void* in = which ? s_feat : t_feat;
    const void* wm = which ? wkc : wq;
    const void* bb = which ? bkc : bq;
    float* out = which ? kout : qout;
    int tid = threadIdx.x;
    for (int i = tid; i < C_ * CM; i += 320) {
        int o = i >> 7, c = i & 127;
        WST[c * CM + o] = ldin(wm, i, isb);
    }
    if (tid < CM) BS[tid] = ldin(bb, tid, isb);
    __syncthreads();
    int w = tid;
    float acc[CM];
    #pragma unroll
    for (int o = 0; o < CM; o++) acc[o] = BS[o];
    int base = (b * C_) * HW + h * W_ + w;
    for (int c = 0; c < C_; c++) {
        float v = ldin(in, base + c * HW, isb);
        #pragma unroll
        for (int o = 0; o < CM; o++) acc[o] += v * WST[c * CM + o];
    }
    float n = 0.f;
    #pragma unroll
    for (int o = 0; o < CM; o++) n += acc[o] * acc[o];
    float s = 1.0f / fmaxf(sqrtf(n), 1e-12f);
    float* op = out + (b * CM) * HW + h * W_ + w;
    #pragma unroll
    for (int o = 0; o < CM; o++) op[o * HW] = acc[o] * s;
}

// ---------------------------------------------------------------------------
// K2: warp + sim + tanh -> Cv; da = sigmoid(w_da @ [q; mean_d(warped)])
// Spill-free restructure: no q[32] array; peak live = qp+dqa+km = 96 floats.
__global__ __launch_bounds__(320, 3) void k_cost(
    const float* __restrict__ qbuf, const float* __restrict__ kbuf,
    const void* __restrict__ metric, const void* __restrict__ disps,
    const void* __restrict__ directs, const void* __restrict__ alpha_p,
    const void* __restrict__ beta_p, const void* __restrict__ w_da,
    const void* __restrict__ b_da,
    float* __restrict__ Cv, float* __restrict__ da)
{
    __shared__ float KS[CM][W_];
    __shared__ float MS[CM][CM];
    __shared__ float WDA[D_ * 64];
    __shared__ float BDA[D_];
    __shared__ float SH[D_];
    int isb = g_flag[0];
    int h = blockIdx.x, b = blockIdx.y, tid = threadIdx.x, w = tid;
    for (int i = tid; i < CM * CM; i += 320) {
        int c = i >> 5, d = i & 31;
        MS[c][d] = 0.5f * (ldin(metric, c * CM + d, isb) + ldin(metric, d * CM + c, isb));
    }
    for (int i = tid; i < D_ * 64; i += 320) WDA[i] = ldin(w_da, i, isb);
    if (tid < D_) {
        BDA[tid] = ldin(b_da, tid, isb);
        SH[tid] = ldin(disps, tid, isb) * ldin(directs, b, isb) * (float)(W_ - 1);
    }
    const float* kp = kbuf + b * QPLANE + h * W_;
    for (int c = 0; c < CM; c++) KS[c][w] = kp[c * HW + w];
    __syncthreads();

    // Phase A: stream q per channel -> qp (metric proj) + dqa (da q-part).
    float qp[CM], dqa[CM];
    #pragma unroll
    for (int d = 0; d < CM; d++) { qp[d] = 0.f; dqa[d] = 0.f; }
    const float* qpp = qbuf + b * QPLANE + h * W_ + w;
    for (int c = 0; c < CM; c++) {
        float v = qpp[c * HW];
        #pragma unroll
        for (int d = 0; d < CM; d++) qp[d] += v * MS[c][d];
        #pragma unroll
        for (int d = 0; d < D_; d++) dqa[d] += v * WDA[d * 64 + c];
    }

    // Phase B: warp + sim + tanh; km accumulates over d. qp dies after this.
    float km[CM];
    #pragma unroll
    for (int c = 0; c < CM; c++) km[c] = 0.f;
    float alpha = ldin(alpha_p, 0, isb), beta = ldin(beta_p, 0, isb);
    float* cvp = Cv + (b * D_) * HW + h * W_ + w;
    for (int d = 0; d < D_; d++) {
        float px = fminf(fmaxf((float)w + SH[d], 0.f), (float)(W_ - 1));
        int x0 = (int)floorf(px);
        int x1 = min(x0 + 1, W_ - 1);
        float f = px - (float)x0;
        float sim = 0.f;
        #pragma unroll
        for (int c = 0; c < CM; c++) {
            float g0 = KS[c][x0], g1 = KS[c][x1];
            float val = g0 * (1.0f - f) + g1 * f;
            sim += qp[c] * val;
            km[c] += val;
        }
        cvp[d * HW] = tanhf(alpha * sim + beta);
    }

    // Phase C: da from dqa + km (qp dead; live = 64 floats).
    #pragma unroll
    for (int c = 0; c < CM; c++) km[c] *= (1.0f / (float)D_);
    float* dap = da + (b * D_) * HW + h * W_ + w;
    for (int d = 0; d < D_; d++) {
        float s = BDA[d] + dqa[d];
        #pragma unroll
        for (int c = 0; c < CM; c++) s += WDA[d * 64 + 32 + c] * km[c];
        dap[d * HW] = sigmoidf_(s);
    }
}

// ---------------------------------------------------------------------------
// K3+K4 fused: Cf = 3x3 conv(Cv)*da -> softmax_d -> P (out) ->
//   cost = w_ex@P+b_ex; g = sigmoid(w_fg@[t;cost]); fused -> g_fused bf16.
// 3x3 conv via direct L2 reads of Cv (no LDS staging, no per-d barriers);
// p[32] stays in registers end-to-end; Pf buffer eliminated.
__global__ __launch_bounds__(320) void k_cfp(
    const float* __restrict__ Cv, const float* __restrict__ da,
    const void* __restrict__ w_cf, const void* __restrict__ b_cf,
    const void* __restrict__ t_feat, const void* __restrict__ w_ex,
    const void* __restrict__ b_ex, const void* __restrict__ w_fg,
    const void* __restrict__ b_fg,
    u16* __restrict__ gf, void* __restrict__ dout)
{
    __shared__ float WEX[C_ * D_];   // [c][d]
    __shared__ float BEX[C_];
    __shared__ float WFG[2 * C_];
    __shared__ float WPRE[D_ + 1];
    int isb = g_flag[0];
    int h = blockIdx.x, b = blockIdx.y, tid = threadIdx.x, w = tid;
    for (int i = tid; i < C_ * D_; i += 320) WEX[i] = ldin(w_ex, i, isb);
    if (tid < C_) BEX[tid] = ldin(b_ex, tid, isb);
    for (int i = tid; i < 2 * C_; i += 320) WFG[i] = ldin(w_fg, i, isb);
    __syncthreads();
    if (tid < D_) {
        float s = 0.f;
        for (int c = 0; c < C_; c++) s += WFG[C_ + c] * WEX[c * D_ + tid];
        WPRE[tid] = s;
    } else if (tid == D_) {
        float s = 0.f;
        for (int c = 0; c < C_; c++) s += WFG[C_ + c] * BEX[c];
        WPRE[D_] = s;
    }
    __syncthreads();

    // 3x3 conv + da, direct from L2 (tap order == old staged version)
    float wcf[9];
    #pragma unroll
    for (int i = 0; i < 9; i++) wcf[i] = ldin(w_cf, i, isb);
    float bcf = ldin(b_cf, 0, isb);
    int wm1 = (w > 0), wp1 = (w < W_ - 1);
    float vals[D_];
    #pragma unroll 4
    for (int d = 0; d < D_; d++) {
        const float* base = Cv + ((b * D_ + d) * H_) * W_;
        float s = bcf;
        #pragma unroll
        for (int r = 0; r < 3; r++) {
            int hh = h + r - 1;
            if (hh >= 0 && hh < H_) {
                const float* rp = base + hh * W_ + w;
                if (wm1) s += rp[-1] * wcf[r * 3 + 0];
                s += rp[0] * wcf[r * 3 + 1];
                if (wp1) s += rp[1] * wcf[r * 3 + 2];
            }
        }
        vals[d] = s * da[((b * D_ + d) * H_ + h) * W_ + w];
    }

    // softmax over d (in registers)
    float m = vals[0];
    #pragma unroll
    for (int d = 1; d < D_; d++) m = fmaxf(m, vals[d]);
    float sum = 0.f;
    #pragma unroll
    for (int d = 0; d < D_; d++) { vals[d] = expf(vals[d] - m); sum += vals[d]; }
    float inv = 1.0f / sum;
    int o = (b * D_) * HW + h * W_ + w;
    #pragma unroll
    for (int d = 0; d < D_; d++) {
        vals[d] *= inv;
        stout(dout, XN + o + d * HW, vals[d], isb);
    }

    // fuse: gacc via WPRE fold, then outputs
    int tbase = (b * C_) * HW + h * W_ + w;
    float gacc = ldin(b_fg, 0, isb) + WPRE[D_];
    #pragma unroll
    for (int d = 0; d < D_; d++) gacc += WPRE[d] * vals[d];
    for (int c = 0; c < C_; c++)
        gacc += WFG[c] * ldin(t_feat, tbase + c * HW, isb);
    float g = sigmoidf_(gacc);
    unsigned int* gfo = (unsigned int*)gf + ((b * H_ + h) * W_ + w) * 64;
    for (int c = 0; c < C_; c += 2) {
        float c0 = BEX[c], c1 = BEX[c + 1];
        #pragma unroll
        for (int d = 0; d < D_; d++) {
            c0 += WEX[c * D_ + d] * vals[d];
            c1 += WEX[(c + 1) * D_ + d] * vals[d];
        }
        float t0 = ldin(t_feat, tbase + c * HW, isb);
        float t1 = ldin(t_feat, tbase + (c + 1) * HW, isb);
        float v0 = g * t0 + (1.0f - g) * c0;
        float v1 = g * t1 + (1.0f - g) * c1;
        gfo[c >> 1] = ((unsigned int)bfbits(v1) << 16) | bfbits(v0);
    }
}

// ---------------------------------------------------------------------------
// K5: x = conv3x3(fused)+b_rd via MFMA implicit GEMM. (verified round-7 ver.)
// grid (10, 24, 4): 32w x 4h x 128co tile; block 128 (2 waves).
// Wave tile: 64 px x 128 co = 4 m-tiles x 8 n-tiles of 16x16x32 bf16 MFMA.
// LDS: input halo 6x34x32ci (pad->40) + weights 128co x 32ci (pad->40).
__global__ __launch_bounds__(128, 2) void k_conv3(
    const u16* __restrict__ gf, const u16* __restrict__ gw,
    const void* __restrict__ b_rd, float* __restrict__ xf)
{
    __shared__ u16 IN[6 * 34 * 40];
    __shared__ u16 WS[128 * 40];
    int isb = g_flag[0];
    int tid = threadIdx.x;
    int wave = tid >> 6, lane = tid & 63;
    int l15 = lane & 15, kq = lane >> 4;
    int w0 = blockIdx.x * 32, h0 = blockIdx.y * 4, b = blockIdx.z;

    f4 acc[4][8];
    #pragma unroll
    for (int mt = 0; mt < 4; mt++)
        #pragma unroll
        for (int nt = 0; nt < 8; nt++) acc[mt][nt] = (f4){0.f, 0.f, 0.f, 0.f};

    float bias[8];
    #pragma unroll
    for (int nt = 0; nt < 8; nt++) bias[nt] = ldin(b_rd, nt * 16 + l15, isb);

    for (int cb = 0; cb < 128; cb += 32) {
        __syncthreads();
        // stage input halo chunk: 6 rows x 34 cols x 32 ci (16B per thread-item)
        for (int s = tid; s < 204 * 4; s += 128) {
            int p = s >> 2, q = s & 3;
            int hp = p / 34, wp = p - hp * 34;
            int hg = h0 - 1 + hp, wg = w0 - 1 + wp;
            uint4 v = make_uint4(0u, 0u, 0u, 0u);
            if (hg >= 0 && hg < H_ && wg >= 0 && wg < W_)
                v = *(const uint4*)(gf + ((((b * H_ + hg) * W_ + wg) << 7) + cb + q * 8));
            *(uint4*)(&IN[(hp * 34 + wp) * 40 + q * 8]) = v;
        }
        for (int pos = 0; pos < 9; pos++) {
            __syncthreads();
            for (int s = tid; s < 128 * 4; s += 128) {
                int co = s >> 2, q = s & 3;
                *(uint4*)(&WS[co * 40 + q * 8]) =
                    *(const uint4*)(gw + (((pos * 128 + co) << 7) + cb + q * 8));
            }
            __syncthreads();
            int kh = pos / 3, kw = pos - kh * 3;
            bf16x8 bfr[8];
            #pragma unroll
            for (int nt = 0; nt < 8; nt++)
                bfr[nt] = *(bf16x8*)(&WS[(nt * 16 + l15) * 40 + kq * 8]);
            #pragma unroll
            for (int mt = 0; mt < 4; mt++) {
                int px = wave * 64 + mt * 16 + l15;
                int row = (px >> 5) + kh, col = (px & 31) + kw;
                bf16x8 afr = *(bf16x8*)(&IN[(row * 34 + col) * 40 + kq * 8]);
                #pragma unroll
                for (int nt = 0; nt < 8; nt++)
                    acc[mt][nt] = __builtin_amdgcn_mfma_f32_16x16x32_bf16(
                        afr, bfr[nt], acc[mt][nt], 0, 0, 0);
            }
        }
    }
    // epilogue: bias, store x (f32 NCHW), SE partial sums
    #pragma unroll
    for (int nt = 0; nt < 8; nt++) {
        int co = nt * 16 + l15;
        float ps = 0.f;
        #pragma unroll
        for (int mt = 0; mt < 4; mt++) {
            #pragma unroll
            for (int r = 0; r < 4; r++) {
                int px = wave * 64 + mt * 16 + kq * 4 + r;
                float v = acc[mt][nt][r] + bias[nt];
                ps += v;
                xf[((b * C_ + co) * H_ + h0 + (px >> 5)) * W_ + w0 + (px & 31)] = v;
            }
        }
        ps += __shfl_xor(ps, 16);
        ps += __shfl_xor(ps, 32);
        if (lane < 16) atomicAdd(&g_ysum[b * C_ + co], ps);
    }
}

// ---------------------------------------------------------------------------
// K6: SE scale per (b,c)
__global__ __launch_bounds__(512) void k_se(
    const void* __restrict__ w_se1, const void* __restrict__ w_se2)
{
    __shared__ float YM[B_ * C_];
    __shared__ float Y1[B_ * 8];
    int isb = g_flag[0];
    int tid = threadIdx.x;
    YM[tid] = g_ysum[tid] * (1.0f / (float)HW);
    __syncthreads();
    if (tid < 32) {
        int b = tid >> 3, j = tid & 7;
        float s = 0.f;
        for (int c = 0; c < C_; c++) s += YM[b * C_ + c] * ldin(w_se1, j * C_ + c, isb);
        Y1[tid] = fmaxf(s, 0.f);
    }
    __syncthreads();
    int b = tid >> 7, c = tid & 127;
    float s = 0.f;
    #pragma unroll
    for (int j = 0; j < 8; j++) s += Y1[b * 8 + j] * ldin(w_se2, c * 8 + j, isb);
    g_se[tid] = sigmoidf_(s);
}

// K7: out_x = elu(xf32 * se), vectorized x4 (HW % 4 == 0 -> same plane)
__global__ __launch_bounds__(256) void k_elu(
    const float* __restrict__ xf, void* __restrict__ dout)
{
    int isb = g_flag[0];
    int i4 = blockIdx.x * 256 + threadIdx.x;
    if (i4 >= XN / 4) return;
    int idx = i4 * 4;
    float se = g_se[idx / HW];
    f4 v = *(const f4*)(xf + idx);
    float r[4];
    #pragma unroll
    for (int j = 0; j < 4; j++) {
        float u = v[j] * se;
        r[j] = u > 0.f ? u : expm1f(u);
    }
    if (isb) {
        unsigned int lo = ((unsigned int)bfbits(r[1]) << 16) | bfbits(r[0]);
        unsigned int hi = ((unsigned int)bfbits(r[3]) << 16) | bfbits(r[2]);
        uint2 pk; pk.x = lo; pk.y = hi;
        *(uint2*)((u16*)dout + idx) = pk;
    } else {
        f4 o; o[0] = r[0]; o[1] = r[1]; o[2] = r[2]; o[3] = r[3];
        *(f4*)((float*)dout + idx) = o;
    }
}

// ---------------------------------------------------------------------------
extern "C" void kernel_launch(void* const* d_in, const int* in_sizes, int n_in,
                              void* d_out, int out_size, void* d_ws, size_t ws_size,
                              hipStream_t stream)
{
    const void* t_feat  = d_in[0];
    const void* s_feat  = d_in[1];
    const void* directs = d_in[2];
    /* d_in[3] image_shape: unused */
    const void* disps   = d_in[4];
    const void* wq      = d_in[5];
    const void* bq      = d_in[6];
    const void* wkc     = d_in[7];
    const void* bkc     = d_in[8];
    const void* metric  = d_in[9];
    const void* alpha   = d_in[10];
    const void* beta    = d_in[11];
    const void* w_cf    = d_in[12];
    const void* b_cf    = d_in[13];
    const void* w_da    = d_in[14];
    const void* b_da    = d_in[15];
    const void* w_ex    = d_in[16];
    const void* b_ex    = d_in[17];
    const void* w_fg    = d_in[18];
    const void* b_fg    = d_in[19];
    const void* w_rd    = d_in[20];
    const void* b_rd    = d_in[21];
    const void* w_se1   = d_in[22];
    const void* w_se2   = d_in[23];
    (void)in_sizes; (void)n_in; (void)out_size; (void)d_ws; (void)ws_size;

    float* base = nullptr;
    (void)hipGetSymbolAddress((void**)&base, HIP_SYMBOL(g_scratch));
    u16* gf = nullptr;
    (void)hipGetSymbolAddress((void**)&gf, HIP_SYMBOL(g_fused));
    u16* gw = nullptr;
    (void)hipGetSymbolAddress((void**)&gw, HIP_SYMBOL(g_wt));
    float* qb = base;
    float* kb = base + PLN;
    float* Cv = base + 2 * PLN;
    float* da = base + 3 * PLN;
    float* xf = base + 4 * PLN;

    k_detect<<<1, 256, 0, stream>>>(t_feat, wq);
    k_wprep<<<576, 256, 0, stream>>>(w_rd, gw);
    k_qk<<<dim3(H_, B_, 2), 320, 0, stream>>>(t_feat, s_feat, wq, bq, wkc, bkc, qb, kb);
    k_cost<<<dim3(H_, B_), 320, 0, stream>>>(qb, kb, metric, disps, directs,
                                             alpha, beta, w_da, b_da, Cv, da);
    k_cfp<<<dim3(H_, B_), 320, 0, stream>>>(Cv, da, w_cf, b_cf, t_feat,
                                            w_ex, b_ex, w_fg, b_fg, gf, d_out);
    k_conv3<<<dim3(10, 24, 4), 128, 0, stream>>>(gf, gw, b_rd, xf);
    k_se<<<1, 512, 0, stream>>>(w_se1, w_se2);
    k_elu<<<(XN / 4 + 255) / 256, 256, 0, stream>>>(xf, d_out);
}

// Round 9
// 608.697 us; speedup vs baseline: 1.1476x; 1.0227x over previous
//
#include <hip/hip_runtime.h>
#include <hip/hip_bf16.h>
#include <math.h>

// HMF block, round 12 (resubmit — previous bench was an infra failure, no
// counters returned). Round-11 post-mortem: k_cfp's `#pragma unroll 4`
// conv loop left vals[d] runtime-indexed -> whole array demoted to scratch
// (VGPR_Count=56, WRITE 132 MB vs ideal ~40, the rule-#20 signature).
// Fix: FULL unroll of the conv d-loop (all vals[] accesses compile-time
// indexed) + __launch_bounds__(320,2) (cap 256 > ~130 live set).
// Everything else identical to round 11.

typedef __hip_bfloat16 bf16;
typedef unsigned short u16;
typedef __attribute__((ext_vector_type(8))) __bf16 bf16x8;
typedef __attribute__((ext_vector_type(4))) float f4;

#define DEVI static __device__ __forceinline__
DEVI float bf2f(bf16 x) { return __bfloat162float(x); }
DEVI bf16  f2bf(float x) { return __float2bfloat16(x); }
DEVI u16 bfbits(float x) { bf16 h = f2bf(x); return *(u16*)&h; }
DEVI float sigmoidf_(float x) { return 1.0f / (1.0f + expf(-x)); }

constexpr int B_ = 4, C_ = 128, H_ = 96, W_ = 320, CM = 32, D_ = 32;
constexpr int HW = H_ * W_;              // 30720
constexpr int QPLANE = CM * HW;          // 983040
constexpr int XN = B_ * C_ * HW;         // 15728640
constexpr int PLN = B_ * D_ * HW;        // 3932160

// scratch slots (floats): q=0 | k=1 | Cv=2 | da=3 ; xf overlays 4-7.
__device__ __align__(16) float g_scratch[8 * PLN];
__device__ __align__(16) u16   g_fused[XN];          // bf16 NHWC
__device__ __align__(16) u16   g_wt[9 * 128 * 128];  // bf16 [pos][co][ci]
__device__ float g_ysum[512];
__device__ float g_se[512];
__device__ int   g_flag[1];

DEVI float ldin(const void* p, int i, int isb) {
    float v;
    if (isb) v = bf2f(((const bf16*)p)[i]);
    else     v = ((const float*)p)[i];
    return v;
}
DEVI void stout(void* p, int i, float v, int isb) {
    if (isb) ((bf16*)p)[i] = f2bf(v);
    else     ((float*)p)[i] = v;
}

// ---------------------------------------------------------------------------
// K0: dtype detect (t_feat + wq) + ysum zero.
__global__ __launch_bounds__(256) void k_detect(
    const void* __restrict__ t, const void* __restrict__ wqp)
{
    __shared__ int bad;
    int tid = threadIdx.x;
    if (tid == 0) bad = 0;
    __syncthreads();
    int mybad = 0;
    for (int i = tid; i < 4096; i += 256) {
        float v = bf2f(((const bf16*)t)[i]);
        if (!(v == v) || fabsf(v) > 64.0f) mybad = 1;
        float u = bf2f(((const bf16*)wqp)[i]);
        if (!(u == u) || fabsf(u) > 64.0f) mybad = 1;
    }
    if (mybad) atomicOr(&bad, 1);
    g_ysum[tid] = 0.f;
    g_ysum[tid + 256] = 0.f;
    __syncthreads();
    if (tid == 0) g_flag[0] = bad ? 0 : 1;
}

// K0b: weight transform w_rd[co][ci][pos] -> g_wt[pos][co][ci] (bf16)
__global__ __launch_bounds__(256) void k_wprep(
    const void* __restrict__ w_rd, u16* __restrict__ gw)
{
    int isb = g_flag[0];
    int i = blockIdx.x * 256 + threadIdx.x;
    if (i >= 9 * 128 * 128) return;
    int pos = i >> 14, rem = i & 16383, co = rem >> 7, ci = rem & 127;
    gw[i] = bfbits(ldin(w_rd, (co * 128 + ci) * 9 + pos, isb));
}

// ---------------------------------------------------------------------------
// K1: q = l2norm(conv1x1(t,wq,bq)), k = l2norm(conv1x1(s,wkc,bkc))
__global__ __launch_bounds__(320) void k_qk(
    const void* __restrict__ t_feat, const void* __restrict__ s_feat,
    const void* __restrict__ wq, const void* __restrict__ bq,
    const void* __restrict__ wkc, const void* __restrict__ bkc,
    float* __restrict__ qout, float* __restrict__ kout)
{
    __shared__ float WST[C_ * CM];   // [c][o]
    __shared__ float BS[CM];
    int isb = g_flag[0];
    int h = blockIdx.x, b = blockIdx.y, which = blockIdx.z;
    const void* in = which ? s_feat : t_feat;
    const void* wm = which ? wkc : wq;
    const void* bb = which ? bkc : bq;
    float* out = which ? kout : qout;
    int tid = threadIdx.x;
    for (int i = tid; i < C_ * CM; i += 320) {
        int o = i >> 7, c = i & 127;
        WST[c * CM + o] = ldin(wm, i, isb);
    }
    if (tid < CM) BS[tid] = ldin(bb, tid, isb);
    __syncthreads();
    int w = tid;
    float acc[CM];
    #pragma unroll
    for (int o = 0; o < CM; o++) acc[o] = BS[o];
    int base = (b * C_) * HW + h * W_ + w;
    for (int c = 0; c < C_; c++) {
        float v = ldin(in, base + c * HW, isb);
        #pragma unroll
        for (int o = 0; o < CM; o++) acc[o] += v * WST[c * CM + o];
    }
    float n = 0.f;
    #pragma unroll
    for (int o = 0; o < CM; o++) n += acc[o] * acc[o];
    float s = 1.0f / fmaxf(sqrtf(n), 1e-12f);
    float* op = out + (b * CM) * HW + h * W_ + w;
    #pragma unroll
    for (int o = 0; o < CM; o++) op[o * HW] = acc[o] * s;
}

// ---------------------------------------------------------------------------
// K2: warp + sim + tanh -> Cv; da = sigmoid(w_da @ [q; mean_d(warped)])
// Spill-free restructure: no q[32] array; peak live = qp+dqa+km = 96 floats.
__global__ __launch_bounds__(320, 3) void k_cost(
    const float* __restrict__ qbuf, const float* __restrict__ kbuf,
    const void* __restrict__ metric, const void* __restrict__ disps,
    const void* __restrict__ directs, const void* __restrict__ alpha_p,
    const void* __restrict__ beta_p, const void* __restrict__ w_da,
    const void* __restrict__ b_da,
    float* __restrict__ Cv, float* __restrict__ da)
{
    __shared__ float KS[CM][W_];
    __shared__ float MS[CM][CM];
    __shared__ float WDA[D_ * 64];
    __shared__ float BDA[D_];
    __shared__ float SH[D_];
    int isb = g_flag[0];
    int h = blockIdx.x, b = blockIdx.y, tid = threadIdx.x, w = tid;
    for (int i = tid; i < CM * CM; i += 320) {
        int c = i >> 5, d = i & 31;
        MS[c][d] = 0.5f * (ldin(metric, c * CM + d, isb) + ldin(metric, d * CM + c, isb));
    }
    for (int i = tid; i < D_ * 64; i += 320) WDA[i] = ldin(w_da, i, isb);
    if (tid < D_) {
        BDA[tid] = ldin(b_da, tid, isb);
        SH[tid] = ldin(disps, tid, isb) * ldin(directs, b, isb) * (float)(W_ - 1);
    }
    const float* kp = kbuf + b * QPLANE + h * W_;
    for (int c = 0; c < CM; c++) KS[c][w] = kp[c * HW + w];
    __syncthreads();

    // Phase A: stream q per channel -> qp (metric proj) + dqa (da q-part).
    float qp[CM], dqa[CM];
    #pragma unroll
    for (int d = 0; d < CM; d++) { qp[d] = 0.f; dqa[d] = 0.f; }
    const float* qpp = qbuf + b * QPLANE + h * W_ + w;
    for (int c = 0; c < CM; c++) {
        float v = qpp[c * HW];
        #pragma unroll
        for (int d = 0; d < CM; d++) qp[d] += v * MS[c][d];
        #pragma unroll
        for (int d = 0; d < D_; d++) dqa[d] += v * WDA[d * 64 + c];
    }

    // Phase B: warp + sim + tanh; km accumulates over d. qp dies after this.
    float km[CM];
    #pragma unroll
    for (int c = 0; c < CM; c++) km[c] = 0.f;
    float alpha = ldin(alpha_p, 0, isb), beta = ldin(beta_p, 0, isb);
    float* cvp = Cv + (b * D_) * HW + h * W_ + w;
    for (int d = 0; d < D_; d++) {
        float px = fminf(fmaxf((float)w + SH[d], 0.f), (float)(W_ - 1));
        int x0 = (int)floorf(px);
        int x1 = min(x0 + 1, W_ - 1);
        float f = px - (float)x0;
        float sim = 0.f;
        #pragma unroll
        for (int c = 0; c < CM; c++) {
            float g0 = KS[c][x0], g1 = KS[c][x1];
            float val = g0 * (1.0f - f) + g1 * f;
            sim += qp[c] * val;
            km[c] += val;
        }
        cvp[d * HW] = tanhf(alpha * sim + beta);
    }

    // Phase C: da from dqa + km (qp dead; live = 64 floats).
    #pragma unroll
    for (int c = 0; c < CM; c++) km[c] *= (1.0f / (float)D_);
    float* dap = da + (b * D_) * HW + h * W_ + w;
    for (int d = 0; d < D_; d++) {
        float s = BDA[d] + dqa[d];
        #pragma unroll
        for (int c = 0; c < CM; c++) s += WDA[d * 64 + 32 + c] * km[c];
        dap[d * HW] = sigmoidf_(s);
    }
}

// ---------------------------------------------------------------------------
// K3+K4 fused: Cf = 3x3 conv(Cv)*da -> softmax_d -> P (out) ->
//   cost = w_ex@P+b_ex; g = sigmoid(w_fg@[t;cost]); fused -> g_fused bf16.
// Conv d-loop FULLY unrolled so vals[] is compile-time indexed everywhere
// (rule #20); launch_bounds(320,2) caps regs at 256 (> ~130 live).
__global__ __launch_bounds__(320, 2) void k_cfp(
    const float* __restrict__ Cv, const float* __restrict__ da,
    const void* __restrict__ w_cf, const void* __restrict__ b_cf,
    const void* __restrict__ t_feat, const void* __restrict__ w_ex,
    const void* __restrict__ b_ex, const void* __restrict__ w_fg,
    const void* __restrict__ b_fg,
    u16* __restrict__ gf, void* __restrict__ dout)
{
    __shared__ float WEX[C_ * D_];   // [c][d]
    __shared__ float BEX[C_];
    __shared__ float WFG[2 * C_];
    __shared__ float WPRE[D_ + 1];
    int isb = g_flag[0];
    int h = blockIdx.x, b = blockIdx.y, tid = threadIdx.x, w = tid;
    for (int i = tid; i < C_ * D_; i += 320) WEX[i] = ldin(w_ex, i, isb);
    if (tid < C_) BEX[tid] = ldin(b_ex, tid, isb);
    for (int i = tid; i < 2 * C_; i += 320) WFG[i] = ldin(w_fg, i, isb);
    __syncthreads();
    if (tid < D_) {
        float s = 0.f;
        for (int c = 0; c < C_; c++) s += WFG[C_ + c] * WEX[c * D_ + tid];
        WPRE[tid] = s;
    } else if (tid == D_) {
        float s = 0.f;
        for (int c = 0; c < C_; c++) s += WFG[C_ + c] * BEX[c];
        WPRE[D_] = s;
    }
    __syncthreads();

    // 3x3 conv + da, direct from L2 (tap order == old staged version).
    // FULL unroll: vals[d] must be compile-time indexed (rule #20).
    float wcf[9];
    #pragma unroll
    for (int i = 0; i < 9; i++) wcf[i] = ldin(w_cf, i, isb);
    float bcf = ldin(b_cf, 0, isb);
    int wm1 = (w > 0), wp1 = (w < W_ - 1);
    float vals[D_];
    #pragma unroll
    for (int d = 0; d < D_; d++) {
        const float* base = Cv + ((b * D_ + d) * H_) * W_;
        float s = bcf;
        #pragma unroll
        for (int r = 0; r < 3; r++) {
            int hh = h + r - 1;
            if (hh >= 0 && hh < H_) {
                const float* rp = base + hh * W_ + w;
                if (wm1) s += rp[-1] * wcf[r * 3 + 0];
                s += rp[0] * wcf[r * 3 + 1];
                if (wp1) s += rp[1] * wcf[r * 3 + 2];
            }
        }
        vals[d] = s * da[((b * D_ + d) * H_ + h) * W_ + w];
    }

    // softmax over d (in registers)
    float m = vals[0];
    #pragma unroll
    for (int d = 1; d < D_; d++) m = fmaxf(m, vals[d]);
    float sum = 0.f;
    #pragma unroll
    for (int d = 0; d < D_; d++) { vals[d] = expf(vals[d] - m); sum += vals[d]; }
    float inv = 1.0f / sum;
    int o = (b * D_) * HW + h * W_ + w;
    #pragma unroll
    for (int d = 0; d < D_; d++) {
        vals[d] *= inv;
        stout(dout, XN + o + d * HW, vals[d], isb);
    }

    // fuse: gacc via WPRE fold, then outputs
    int tbase = (b * C_) * HW + h * W_ + w;
    float gacc = ldin(b_fg, 0, isb) + WPRE[D_];
    #pragma unroll
    for (int d = 0; d < D_; d++) gacc += WPRE[d] * vals[d];
    for (int c = 0; c < C_; c++)
        gacc += WFG[c] * ldin(t_feat, tbase + c * HW, isb);
    float g = sigmoidf_(gacc);
    unsigned int* gfo = (unsigned int*)gf + ((b * H_ + h) * W_ + w) * 64;
    for (int c = 0; c < C_; c += 2) {
        float c0 = BEX[c], c1 = BEX[c + 1];
        #pragma unroll
        for (int d = 0; d < D_; d++) {
            c0 += WEX[c * D_ + d] * vals[d];
            c1 += WEX[(c + 1) * D_ + d] * vals[d];
        }
        float t0 = ldin(t_feat, tbase + c * HW, isb);
        float t1 = ldin(t_feat, tbase + (c + 1) * HW, isb);
        float v0 = g * t0 + (1.0f - g) * c0;
        float v1 = g * t1 + (1.0f - g) * c1;
        gfo[c >> 1] = ((unsigned int)bfbits(v1) << 16) | bfbits(v0);
    }
}

// ---------------------------------------------------------------------------
// K5: x = conv3x3(fused)+b_rd via MFMA implicit GEMM. (verified round-7 ver.)
// grid (10, 24, 4): 32w x 4h x 128co tile; block 128 (2 waves).
// Wave tile: 64 px x 128 co = 4 m-tiles x 8 n-tiles of 16x16x32 bf16 MFMA.
// LDS: input halo 6x34x32ci (pad->40) + weights 128co x 32ci (pad->40).
__global__ __launch_bounds__(128, 2) void k_conv3(
    const u16* __restrict__ gf, const u16* __restrict__ gw,
    const void* __restrict__ b_rd, float* __restrict__ xf)
{
    __shared__ u16 IN[6 * 34 * 40];
    __shared__ u16 WS[128 * 40];
    int isb = g_flag[0];
    int tid = threadIdx.x;
    int wave = tid >> 6, lane = tid & 63;
    int l15 = lane & 15, kq = lane >> 4;
    int w0 = blockIdx.x * 32, h0 = blockIdx.y * 4, b = blockIdx.z;

    f4 acc[4][8];
    #pragma unroll
    for (int mt = 0; mt < 4; mt++)
        #pragma unroll
        for (int nt = 0; nt < 8; nt++) acc[mt][nt] = (f4){0.f, 0.f, 0.f, 0.f};

    float bias[8];
    #pragma unroll
    for (int nt = 0; nt < 8; nt++) bias[nt] = ldin(b_rd, nt * 16 + l15, isb);

    for (int cb = 0; cb < 128; cb += 32) {
        __syncthreads();
        // stage input halo chunk: 6 rows x 34 cols x 32 ci (16B per thread-item)
        for (int s = tid; s < 204 * 4; s += 128) {
            int p = s >> 2, q = s & 3;
            int hp = p / 34, wp = p - hp * 34;
            int hg = h0 - 1 + hp, wg = w0 - 1 + wp;
            uint4 v = make_uint4(0u, 0u, 0u, 0u);
            if (hg >= 0 && hg < H_ && wg >= 0 && wg < W_)
                v = *(const uint4*)(gf + ((((b * H_ + hg) * W_ + wg) << 7) + cb + q * 8));
            *(uint4*)(&IN[(hp * 34 + wp) * 40 + q * 8]) = v;
        }
        for (int pos = 0; pos < 9; pos++) {
            __syncthreads();
            for (int s = tid; s < 128 * 4; s += 128) {
                int co = s >> 2, q = s & 3;
                *(uint4*)(&WS[co * 40 + q * 8]) =
                    *(const uint4*)(gw + (((pos * 128 + co) << 7) + cb + q * 8));
            }
            __syncthreads();
            int kh = pos / 3, kw = pos - kh * 3;
            bf16x8 bfr[8];
            #pragma unroll
            for (int nt = 0; nt < 8; nt++)
                bfr[nt] = *(bf16x8*)(&WS[(nt * 16 + l15) * 40 + kq * 8]);
            #pragma unroll
            for (int mt = 0; mt < 4; mt++) {
                int px = wave * 64 + mt * 16 + l15;
                int row = (px >> 5) + kh, col = (px & 31) + kw;
                bf16x8 afr = *(bf16x8*)(&IN[(row * 34 + col) * 40 + kq * 8]);
                #pragma unroll
                for (int nt = 0; nt < 8; nt++)
                    acc[mt][nt] = __builtin_amdgcn_mfma_f32_16x16x32_bf16(
                        afr, bfr[nt], acc[mt][nt], 0, 0, 0);
            }
        }
    }
    // epilogue: bias, store x (f32 NCHW), SE partial sums
    #pragma unroll
    for (int nt = 0; nt < 8; nt++) {
        int co = nt * 16 + l15;
        float ps = 0.f;
        #pragma unroll
        for (int mt = 0; mt < 4; mt++) {
            #pragma unroll
            for (int r = 0; r < 4; r++) {
                int px = wave * 64 + mt * 16 + kq * 4 + r;
                float v = acc[mt][nt][r] + bias[nt];
                ps += v;
                xf[((b * C_ + co) * H_ + h0 + (px >> 5)) * W_ + w0 + (px & 31)] = v;
            }
        }
        ps += __shfl_xor(ps, 16);
        ps += __shfl_xor(ps, 32);
        if (lane < 16) atomicAdd(&g_ysum[b * C_ + co], ps);
    }
}

// ---------------------------------------------------------------------------
// K6: SE scale per (b,c)
__global__ __launch_bounds__(512) void k_se(
    const void* __restrict__ w_se1, const void* __restrict__ w_se2)
{
    __shared__ float YM[B_ * C_];
    __shared__ float Y1[B_ * 8];
    int isb = g_flag[0];
    int tid = threadIdx.x;
    YM[tid] = g_ysum[tid] * (1.0f / (float)HW);
    __syncthreads();
    if (tid < 32) {
        int b = tid >> 3, j = tid & 7;
        float s = 0.f;
        for (int c = 0; c < C_; c++) s += YM[b * C_ + c] * ldin(w_se1, j * C_ + c, isb);
        Y1[tid] = fmaxf(s, 0.f);
    }
    __syncthreads();
    int b = tid >> 7, c = tid & 127;
    float s = 0.f;
    #pragma unroll
    for (int j = 0; j < 8; j++) s += Y1[b * 8 + j] * ldin(w_se2, c * 8 + j, isb);
    g_se[tid] = sigmoidf_(s);
}

// K7: out_x = elu(xf32 * se), vectorized x4 (HW % 4 == 0 -> same plane)
__global__ __launch_bounds__(256) void k_elu(
    const float* __restrict__ xf, void* __restrict__ dout)
{
    int isb = g_flag[0];
    int i4 = blockIdx.x * 256 + threadIdx.x;
    if (i4 >= XN / 4) return;
    int idx = i4 * 4;
    float se = g_se[idx / HW];
    f4 v = *(const f4*)(xf + idx);
    float r[4];
    #pragma unroll
    for (int j = 0; j < 4; j++) {
        float u = v[j] * se;
        r[j] = u > 0.f ? u : expm1f(u);
    }
    if (isb) {
        unsigned int lo = ((unsigned int)bfbits(r[1]) << 16) | bfbits(r[0]);
        unsigned int hi = ((unsigned int)bfbits(r[3]) << 16) | bfbits(r[2]);
        uint2 pk; pk.x = lo; pk.y = hi;
        *(uint2*)((u16*)dout + idx) = pk;
    } else {
        f4 o; o[0] = r[0]; o[1] = r[1]; o[2] = r[2]; o[3] = r[3];
        *(f4*)((float*)dout + idx) = o;
    }
}

// ---------------------------------------------------------------------------
extern "C" void kernel_launch(void* const* d_in, const int* in_sizes, int n_in,
                              void* d_out, int out_size, void* d_ws, size_t ws_size,
                              hipStream_t stream)
{
    const void* t_feat  = d_in[0];
    const void* s_feat  = d_in[1];
    const void* directs = d_in[2];
    /* d_in[3] image_shape: unused */
    const void* disps   = d_in[4];
    const void* wq      = d_in[5];
    const void* bq      = d_in[6];
    const void* wkc     = d_in[7];
    const void* bkc     = d_in[8];
    const void* metric  = d_in[9];
    const void* alpha   = d_in[10];
    const void* beta    = d_in[11];
    const void* w_cf    = d_in[12];
    const void* b_cf    = d_in[13];
    const void* w_da    = d_in[14];
    const void* b_da    = d_in[15];
    const void* w_ex    = d_in[16];
    const void* b_ex    = d_in[17];
    const void* w_fg    = d_in[18];
    const void* b_fg    = d_in[19];
    const void* w_rd    = d_in[20];
    const void* b_rd    = d_in[21];
    const void* w_se1   = d_in[22];
    const void* w_se2   = d_in[23];
    (void)in_sizes; (void)n_in; (void)out_size; (void)d_ws; (void)ws_size;

    float* base = nullptr;
    (void)hipGetSymbolAddress((void**)&base, HIP_SYMBOL(g_scratch));
    u16* gf = nullptr;
    (void)hipGetSymbolAddress((void**)&gf, HIP_SYMBOL(g_fused));
    u16* gw = nullptr;
    (void)hipGetSymbolAddress((void**)&gw, HIP_SYMBOL(g_wt));
    float* qb = base;
    float* kb = base + PLN;
    float* Cv = base + 2 * PLN;
    float* da = base + 3 * PLN;
    float* xf = base + 4 * PLN;

    k_detect<<<1, 256, 0, stream>>>(t_feat, wq);
    k_wprep<<<576, 256, 0, stream>>>(w_rd, gw);
    k_qk<<<dim3(H_, B_, 2), 320, 0, stream>>>(t_feat, s_feat, wq, bq, wkc, bkc, qb, kb);
    k_cost<<<dim3(H_, B_), 320, 0, stream>>>(qb, kb, metric, disps, directs,
                                             alpha, beta, w_da, b_da, Cv, da);
    k_cfp<<<dim3(H_, B_), 320, 0, stream>>>(Cv, da, w_cf, b_cf, t_feat,
                                            w_ex, b_ex, w_fg, b_fg, gf, d_out);
    k_conv3<<<dim3(10, 24, 4), 128, 0, stream>>>(gf, gw, b_rd, xf);
    k_se<<<1, 512, 0, stream>>>(w_se1, w_se2);
    k_elu<<<(XN / 4 + 255) / 256, 256, 0, stream>>>(xf, d_out);
}